// Round 11
// baseline (244.109 us; speedup 1.0000x reference)
//
#include <hip/hip_runtime.h>
#include <math.h>

#define N 8192
#define M 8192
#define C 96
#define OUT 20
#define LG 2048

#define KP2 192     // stored K per row: [hi(96)|lo(96)] fp16, 24 h8 slots
#define NSPA 4      // y-slices pass A
#define NSPB 4      // y-slices pass B
#define LOG2E 1.4426950408889634f

typedef _Float16 h8 __attribute__((ext_vector_type(8)));
typedef float    f4 __attribute__((ext_vector_type(4)));

// native v_exp_f32 (exp2f = libm-precise __ocml call, ~10 instrs; this is 1)
__device__ __forceinline__ float fexp2(float x) { return __builtin_amdgcn_exp2f(x); }

// async global->LDS, 16B per lane, no VGPR round-trip (m97 path)
__device__ __forceinline__ void gl_lds16(const h8* g, h8* l) {
    __builtin_amdgcn_global_load_lds(
        (const __attribute__((address_space(1))) unsigned int*)g,
        (__attribute__((address_space(3))) unsigned int*)l,
        16, 0, 0);
}

// tile-slot-major h8 index: rows grouped in 128-row tiles, slot-major inside
__device__ __forceinline__ size_t tsm24(int row, int slot) {
    return ((size_t)(row >> 7) * 24 + slot) * 128 + (row & 127);
}

// ---------------- workspace layout (bytes, all 256-aligned) ----------------
constexpr size_t OFF_AL    = 256;
constexpr size_t OFF_UPDF  = OFF_AL    + (size_t)M*3*4;
constexpr size_t OFF_GTC   = OFF_UPDF  + (size_t)M*4;
constexpr size_t OFF_SMI   = OFF_GTC   + (size_t)M*4;
constexpr size_t OFF_PERM  = OFF_SMI   + (size_t)M*4;
constexpr size_t OFF_AP    = OFF_PERM  + (size_t)M*4;            // M x 192 fp16 (tsm24)
constexpr size_t OFF_BQ    = OFF_AP    + (size_t)M*KP2*2;        // N x 192 fp16
constexpr size_t OFF_MFP   = OFF_BQ    + (size_t)N*KP2*2;        // N x 192 fp16
constexpr size_t OFF_MIDH  = OFF_MFP   + (size_t)N*KP2*2;        // (M+256) x 12 hi slots
constexpr size_t OFF_PAV   = OFF_MIDH  + (size_t)(M+256)*192;    // NSPA x M
constexpr size_t OFF_PAI   = OFF_PAV   + (size_t)NSPA*M*4;
constexpr size_t OFF_PB    = OFF_PAI   + (size_t)NSPA*M*4;       // NSPB x N x 20
constexpr size_t OFF_POS   = OFF_PB    + (size_t)NSPB*N*OUT*4;
constexpr size_t OFF_MAXV  = OFF_POS   + (size_t)N*4;
constexpr size_t OFF_AMAX  = OFF_MAXV  + (size_t)N*4;
constexpr size_t OFF_FLAGS = OFF_AMAX  + (size_t)N*4;
constexpr size_t OFF_CNT   = OFF_FLAGS + 256;
constexpr size_t OFF_META  = OFF_CNT   + 256;   // [0]=Mact [1]=nmacro [2..21]=cursor
constexpr size_t OFF_NQ4   = OFF_META  + 256;                    // N x float4 {ox,oy,oz,nmf2}
constexpr size_t OFF_SIDEQ = OFF_NQ4   + (size_t)N*16;           // (M+256) x float4 {m2,mx,my,mz}
constexpr size_t OFF_SIDEC = OFF_SIDEQ + (size_t)(M+256)*16;     // (M+256) int cls

// ---------------------------------------------------------------- fused prep
// 1024 blocks x 64 threads, 4 threads/row (16 rows/block): blocks [0,512) do
// the m-side (inline 4x4 inverse + class hist), [512,1024) the n-side.
__global__ void k_prep(const float* __restrict__ ssf, const float* __restrict__ scoords,
                       const float* __restrict__ gt, const int* __restrict__ ran_mask,
                       const float* __restrict__ posses,
                       const float* __restrict__ mf, const float* __restrict__ ori,
                       float* __restrict__ al, _Float16* __restrict__ aP,
                       float* __restrict__ updf, int* __restrict__ gtcls,
                       int* __restrict__ cnt,
                       _Float16* __restrict__ bQ, _Float16* __restrict__ mfP,
                       float4* __restrict__ nq4) {
    const int tt = threadIdx.x;          // 0..63
    if (blockIdx.x < 512) {
        // ---------------- m-side ----------------
        __shared__ int hcnt[OUT];
        __shared__ float sdiff[12];
        if (tt == 0) {   // inline inv(posses[1]) @ posses[0], rows 0..2
            float a[4][8];
            for (int i = 0; i < 4; i++)
                for (int j = 0; j < 4; j++) {
                    a[i][j]     = posses[16 + i*4 + j];
                    a[i][4 + j] = (i == j) ? 1.f : 0.f;
                }
            for (int col = 0; col < 4; col++) {
                int piv = col; float mx = fabsf(a[col][col]);
                for (int r = col + 1; r < 4; r++) {
                    float v = fabsf(a[r][col]);
                    if (v > mx) { mx = v; piv = r; }
                }
                if (piv != col)
                    for (int j = 0; j < 8; j++) { float t2 = a[col][j]; a[col][j] = a[piv][j]; a[piv][j] = t2; }
                float inv = 1.0f / a[col][col];
                for (int j = 0; j < 8; j++) a[col][j] *= inv;
                for (int r = 0; r < 4; r++) {
                    if (r == col) continue;
                    float f = a[r][col];
                    for (int j = 0; j < 8; j++) a[r][j] -= f * a[col][j];
                }
            }
            for (int i = 0; i < 3; i++)
                for (int j = 0; j < 4; j++) {
                    float s2 = 0.f;
                    for (int k = 0; k < 4; k++) s2 += a[i][4 + k] * posses[k*4 + j];
                    sdiff[i*4 + j] = s2;
                }
        }
        if (tt < OUT) hcnt[tt] = 0;
        __syncthreads();
        const int m = blockIdx.x * 16 + (tt >> 2);
        const int h = tt & 3;
        const float4* r4 = (const float4*)(ssf + (size_t)m * C);
        float4 row[6]; float s = 0.f;
        #pragma unroll
        for (int c = 0; c < 6; c++) {
            float4 v = r4[h*6 + c];
            row[c] = v;
            s += v.x*v.x + v.y*v.y + v.z*v.z + v.w*v.w;
        }
        s += __shfl_xor(s, 1, 64);
        s += __shfl_xor(s, 2, 64);
        float scale = 256.0f / sqrtf(s);
        h8* dst = (h8*)aP;
        #pragma unroll
        for (int qq = 0; qq < 3; qq++) {
            int q = h*3 + qq;
            float4 u = row[2*qq], v = row[2*qq+1];
            float xs[8] = {u.x,u.y,u.z,u.w,v.x,v.y,v.z,v.w};
            h8 hi, lo;
            #pragma unroll
            for (int e = 0; e < 8; e++) {
                float xv = xs[e] * scale;
                _Float16 hh = (_Float16)xv;
                hi[e] = hh;
                lo[e] = (_Float16)(xv - (float)hh);
            }
            dst[tsm24(m, q)]      = hi;
            dst[tsm24(m, 12 + q)] = lo;
        }
        if (h == 0) {
            float x = scoords[m*3], y = scoords[m*3+1], z = scoords[m*3+2];
            #pragma unroll
            for (int j = 0; j < 3; j++)
                al[m*3 + j] = sdiff[j*4+0]*x + sdiff[j*4+1]*y + sdiff[j*4+2]*z + sdiff[j*4+3];
            int best = 0; float bv = gt[(size_t)m*OUT];
            #pragma unroll
            for (int k = 1; k < OUT; k++) {
                float v = gt[(size_t)m*OUT + k];
                if (v > bv) { bv = v; best = k; }
            }
            gtcls[m] = best;
            bool upd = (best < 9 || m < LG || ran_mask[m] == 1);
            updf[m] = upd ? 1.f : 0.f;
            if (upd) atomicAdd(&hcnt[best], 1);
        }
        __syncthreads();
        if (tt < OUT) atomicAdd(&cnt[tt], hcnt[tt]);
    } else {
        // ---------------- n-side ----------------
        const int n = (blockIdx.x - 512) * 16 + (tt >> 2);
        const int h = tt & 3;
        const float4* r4 = (const float4*)(mf + (size_t)n * C);
        float4 row[6]; float s = 0.f;
        #pragma unroll
        for (int c = 0; c < 6; c++) {
            float4 v = r4[h*6 + c];
            row[c] = v;
            s += v.x*v.x + v.y*v.y + v.z*v.z + v.w*v.w;
        }
        s += __shfl_xor(s, 1, 64);
        s += __shfl_xor(s, 2, 64);
        if (h == 0) {
            float4 o;
            o.x = ori[n*3]; o.y = ori[n*3+1]; o.z = ori[n*3+2]; o.w = s;
            nq4[n] = o;
        }
        float scn = 256.0f / sqrtf(s);
        h8* dB = (h8*)bQ;
        h8* dF = (h8*)mfP;
        #pragma unroll
        for (int qq = 0; qq < 3; qq++) {
            int q = h*3 + qq;
            float4 u = row[2*qq], v = row[2*qq+1];
            float xs[8] = {u.x,u.y,u.z,u.w,v.x,v.y,v.z,v.w};
            h8 hiN, loN, hiF, loF;
            #pragma unroll
            for (int e = 0; e < 8; e++) {
                float xn = xs[e] * scn;
                _Float16 hn = (_Float16)xn;
                hiN[e] = hn; loN[e] = (_Float16)(xn - (float)hn);
                float xf = xs[e] * 256.0f;
                _Float16 hf = (_Float16)xf;
                hiF[e] = hf; loF[e] = (_Float16)(xf - (float)hf);
            }
            dB[tsm24(n, q)]    = hiN;
            dB[tsm24(n, 12+q)] = loN;
            dF[tsm24(n, q)]    = hiF;
            dF[tsm24(n, 12+q)] = loF;
        }
    }
}

// ---------------------------------------------------------------- pass A: MFMA argmin
// 512 threads (8 waves), 64 m-rows resident, 64-col double-buffered B tiles.
// LDS 76.8 KB -> TWO blocks/CU = two independent barrier domains (while one
// block drains vmcnt at its barrier, the other's 8 waves keep issuing).
// Wave tile 32m x 16n (wm 0..1, wn 0..3). Same per-wave instruction mix as r9.
__global__ __launch_bounds__(512, 4) void k_argmin(
        const _Float16* __restrict__ aP, const _Float16* __restrict__ bQ,
        const float* __restrict__ al, const float4* __restrict__ nq4,
        float* __restrict__ pav, int* __restrict__ pai) {
    __shared__ h8 sA[24*64];           // 24 KB resident (64 m-rows, hi+lo)
    __shared__ h8 sB[2][24*64];        // 2 x 24 KB streamed (64 n-cols/tile)
    __shared__ float xv[4*64];
    __shared__ int   xi[4*64];
    __shared__ float4 sMs[64];         // {4axL,4ayL,4azL,-2|a|^2 L} per m-row
    const int t = threadIdx.x;
    const int wave = t >> 6, lane = t & 63;
    const int col = lane & 15, quad = lane >> 4;
    const int wm = wave >> 2, wn = wave & 3;     // 2m x 4n
    const int m0 = blockIdx.x * 64;
    const int sp = blockIdx.y;

    {   // stage resident A: 64 rows of a 128-row tsm24 group (24 slots x 64)
        const h8* gA = (const h8*)aP + (size_t)(m0 >> 7) * 3072 + (m0 & 127);
        #pragma unroll
        for (int q = 0; q < 3; q++) {
            int idx = q*512 + t;               // 0..1535; per (q,wave): slot const
            int slot = idx >> 6, off = idx & 63;
            gl_lds16(gA + slot*128 + off, sA + idx);
        }
        // first streamed tile (64 n-cols)
        const h8* g = (const h8*)bQ + (size_t)(sp >> 1) * 3072 + (sp & 1) * 64;
        #pragma unroll
        for (int q = 0; q < 3; q++) {
            int idx = q*512 + t;
            int slot = idx >> 6, off = idx & 63;
            gl_lds16(g + slot*128 + off, sB[0] + idx);
        }
    }
    if (t < 64) {   // per-m expanded terms into LDS (log2e pre-folded)
        float ax = al[(m0+t)*3+0], ay = al[(m0+t)*3+1], az = al[(m0+t)*3+2];
        sMs[t] = (float4){4.0f*LOG2E*ax, 4.0f*LOG2E*ay, 4.0f*LOG2E*az,
                          -2.0f*LOG2E*(ax*ax+ay*ay+az*az)};
    }
    float best[8]; int bidx[8];
    #pragma unroll
    for (int e = 0; e < 8; e++) { best[e] = 3.4e38f; bidx[e] = 0; }

    __syncthreads();                       // sA + sB[0] + sMs visible

    // hoist resident-A fragments to registers (loop-invariant): 48 VGPR
    h8 ahR[3][2], aloR[3][2];
    #pragma unroll
    for (int ks = 0; ks < 3; ks++) {
        const int hs = ks*4 + quad;
        #pragma unroll
        for (int i = 0; i < 2; i++) {
            int ml = wm*32 + i*16 + col;
            ahR[ks][i]  = sA[hs*64 + ml];
            aloR[ks][i] = sA[(12+hs)*64 + ml];
        }
    }

    const int NT = (N/64) / NSPA;          // 32 tiles per slice
    int cur = 0;
    f4 acc[2];
    for (int u = 0; u < NT; u++) {
        const int tile = sp + u*NSPA;
        if (u + 1 < NT) {                  // prefetch next tile into other buffer
            const int t2 = sp + (u+1)*NSPA;
            const h8* g = (const h8*)bQ + (size_t)(t2 >> 1) * 3072 + (t2 & 1) * 64;
            #pragma unroll
            for (int q = 0; q < 3; q++) {
                int idx = q*512 + t;
                int slot = idx >> 6, off = idx & 63;
                gl_lds16(g + slot*128 + off, sB[cur^1] + idx);
            }
        }
        acc[0] = (f4){0.f,0.f,0.f,0.f};
        acc[1] = (f4){0.f,0.f,0.f,0.f};

        const h8* sBc = sB[cur];
        #pragma unroll
        for (int ks = 0; ks < 3; ks++) {
            const int hs = ks*4 + quad;        // hi slot; lo slot = 12+hs
            const int r = wn*16 + col;
            h8 bh  = sBc[hs*64 + r];
            h8 blo = sBc[(12+hs)*64 + r];
            #pragma unroll
            for (int i = 0; i < 2; i++) {
                acc[i] = __builtin_amdgcn_mfma_f32_16x16x32_f16(ahR[ks][i],  bh,  acc[i], 0, 0, 0);
                acc[i] = __builtin_amdgcn_mfma_f32_16x16x32_f16(ahR[ks][i],  blo, acc[i], 0, 0, 0);
                acc[i] = __builtin_amdgcn_mfma_f32_16x16x32_f16(aloR[ks][i], bh,  acc[i], 0, 0, 0);
            }
        }
        // epilogue: running per-lane argmin (e-outer, native exp2)
        const int n = tile*64 + wn*16 + col;
        float4 o = nq4[n];
        float bn = -2.0f*LOG2E*(o.x*o.x + o.y*o.y + o.z*o.z);
        #pragma unroll
        for (int e = 0; e < 8; e++) {
            int ml = wm*32 + (e>>2)*16 + quad*4 + (e&3);
            float4 sm = sMs[ml];
            float dot = acc[e>>2][e&3];
            float c = sm.w + bn;
            c = fmaf(sm.z, o.z, c);
            c = fmaf(sm.y, o.y, c);
            c = fmaf(sm.x, o.x, c);
            float sim = fmaf(dot, -(1.0f/65536.0f), 2.0f) - fexp2(c);
            if (sim < best[e]) { best[e] = sim; bidx[e] = n; }
        }
        __syncthreads();      // prefetch landed + all waves done reading sB[cur]
        cur ^= 1;
    }
    // butterfly over 16 col-lanes, once per block
    #pragma unroll
    for (int e = 0; e < 8; e++) {
        float bv = best[e]; int bi = bidx[e];
        #pragma unroll
        for (int d = 1; d < 16; d <<= 1) {
            float ov = __shfl_xor(bv, d, 64);
            int   oi = __shfl_xor(bi, d, 64);
            if (ov < bv || (ov == bv && oi < bi)) { bv = ov; bi = oi; }
        }
        best[e] = bv; bidx[e] = bi;
    }
    if (col == 0) {
        #pragma unroll
        for (int e = 0; e < 8; e++) {
            int ml = wm*32 + (e>>2)*16 + quad*4 + (e&3);
            xv[wn*64 + ml] = best[e];
            xi[wn*64 + ml] = bidx[e];
        }
    }
    __syncthreads();
    if (t < 64) {   // single writer per (sp, m)
        float bv = xv[t]; int bi = xi[t];
        #pragma unroll
        for (int w = 1; w < 4; w++) {
            float v = xv[w*64 + t]; int i2 = xi[w*64 + t];
            if (v < bv || (v == bv && i2 < bi)) { bv = v; bi = i2; }
        }
        pav[(size_t)sp * M + m0 + t] = bv;
        pai[(size_t)sp * M + m0 + t] = bi;
    }
}

// ---------------------------------------------------------------- scan
__global__ void k_scan(const int* __restrict__ cnt, int* __restrict__ meta) {
    if (threadIdx.x != 0 || blockIdx.x != 0) return;
    int run = 0;
    for (int k = 0; k < OUT; k++) { meta[2 + k] = run; run += cnt[k]; }
    meta[0] = run;
    meta[1] = (run + 255) / 256;      // macro-tiles of 256
}

// permute (counting sort placement) + folded 4-way argmin reduce (same grid)
__global__ void k_permute(const float* __restrict__ pav, const int* __restrict__ pai,
                          const int* __restrict__ gtcls, const float* __restrict__ updf,
                          int* __restrict__ meta, int* __restrict__ perm,
                          int* __restrict__ smi, float* __restrict__ out_smi) {
    int m = blockIdx.x * 256 + threadIdx.x;
    if (m >= M) return;
    float best = 3.4e38f; int bidx = 0;
    for (int sp = 0; sp < NSPA; sp++) {
        float v = pav[(size_t)sp * M + m];
        int   i = pai[(size_t)sp * M + m];
        if (v < best || (v == best && i < bidx)) { best = v; bidx = i; }
    }
    smi[m] = bidx;
    out_smi[m] = (float)bidx;
    if (updf[m] == 0.f) return;
    int pos = atomicAdd(&meta[2 + gtcls[m]], 1);
    perm[pos] = m;
}

// gather sorted+compacted mid rows, HI SLOTS ONLY (12/row) into compact midH;
// packs per-row side data {m2,mx,my,mz} + cls for k_uw.
__global__ void k_gather_sorted(const int* __restrict__ meta, const int* __restrict__ perm,
                                const int* __restrict__ smi, const int* __restrict__ gtcls,
                                const _Float16* __restrict__ mfP, const float4* __restrict__ nq4,
                                _Float16* __restrict__ midH,
                                float4* __restrict__ sideQ, int* __restrict__ sideC) {
    int tid = blockIdx.x * 256 + threadIdx.x;
    int rr = tid / 12;
    int q  = tid - rr * 12;          // hi slot 0..11
    int mact = meta[0];
    int mpad = meta[1] * 256;
    if (rr >= mpad) return;
    h8* dst = (h8*)midH;
    size_t didx = ((size_t)(rr >> 7) * 12 + q) * 128 + (rr & 127);
    if (rr < mact) {
        int m = perm[rr];
        int s = smi[m];
        dst[didx] = ((const h8*)mfP)[tsm24(s, q)];
        if (q == 0) {
            float4 o = nq4[s];
            float4 sq;
            sq.x = o.w;                       // |feat|^2
            sq.y = o.x; sq.z = o.y; sq.w = o.z;
            sideQ[rr] = sq;
            sideC[rr] = gtcls[m];
        }
    } else {
        dst[didx] = (h8)(_Float16)0.f;
        if (q == 0) {
            sideQ[rr] = (float4){1e9f, 0.f, 0.f, 0.f};   // fd=1e9 -> w = 0 exactly
            sideC[rr] = 0;
        }
    }
}

// ---------------------------------------------------------------- pass B: MFMA class-binned sums
// 512 threads (8 waves), 64 n-rows resident, 128-col hi-only double-buffered
// mid tiles. LDS 80.4 KB -> two blocks/CU (independent barrier domains).
// Wave tile 32n x 32m (wm 0..1, wn 0..3). Boundary masked class-range reduce;
// e-outer epilogue; native exp2.
__global__ __launch_bounds__(512, 4) void k_uw(
        const _Float16* __restrict__ mfP, const _Float16* __restrict__ midH,
        const float4* __restrict__ nq4,
        const float4* __restrict__ sideQ, const int* __restrict__ sideC,
        const int* __restrict__ meta, float* __restrict__ pb) {
    __shared__ h8 sN[24*64];           // 24 KB resident n-rows (hi+lo)
    __shared__ h8 sB[2][12*128];       // 2 x 24 KB streamed mid tiles (hi, 128 cols)
    __shared__ float bins[64*21];
    __shared__ float4 sSa[64];         // {ox,oy,oz,-8L|o|^2} per n-row
    __shared__ float  sSb[64];         // nmf2 per n-row
    const int t = threadIdx.x;
    const int wave = t >> 6, lane = t & 63;
    const int col = lane & 15, quad = lane >> 4;
    const int wm = wave >> 2, wn = wave & 3;     // 2n x 4m
    const int n0 = blockIdx.x * 64;
    const int sp = blockIdx.y;
    const int nmac2 = meta[1] * 2;     // 128-col tiles

    {   // stage resident n-rows: 64 rows of a 128-row tsm24 group
        const h8* gN = (const h8*)mfP + (size_t)(n0 >> 7) * 3072 + (n0 & 127);
        #pragma unroll
        for (int q = 0; q < 3; q++) {
            int idx = q*512 + t;
            int slot = idx >> 6, off = idx & 63;
            gl_lds16(gN + slot*128 + off, sN + idx);
        }
        if (sp < nmac2) {   // first streamed tile (contiguous 1536 h8)
            const h8* g = (const h8*)midH + (size_t)sp * 1536;
            #pragma unroll
            for (int q = 0; q < 3; q++) gl_lds16(g + q*512 + t, sB[0] + q*512 + t);
        }
    }
    if (t < 64) {   // per-n expanded terms into LDS (log2e pre-folded)
        float4 q = nq4[n0 + t];
        sSa[t] = (float4){q.x, q.y, q.z, -8.0f*LOG2E*(q.x*q.x + q.y*q.y + q.z*q.z)};
        sSb[t] = q.w;
    }
    for (int i = t; i < 64*21; i += 512) bins[i] = 0.f;

    __syncthreads();                   // sN + sB[0] + side + bins visible

    // hoist resident-N fragments to registers (loop-invariant): 48 VGPR
    h8 ahR[3][2], aloR[3][2];
    #pragma unroll
    for (int ks = 0; ks < 3; ks++) {
        const int hs = ks*4 + quad;
        #pragma unroll
        for (int i = 0; i < 2; i++) {
            int ml = wm*32 + i*16 + col;
            ahR[ks][i]  = sN[hs*64 + ml];
            aloR[ks][i] = sN[(12+hs)*64 + ml];
        }
    }

    int cur = 0;
    f4 acc[2][2];
    for (int mt = sp; mt < nmac2; mt += NSPB) {
        const int mb = mt * 128;
        if (mt + NSPB < nmac2) {       // prefetch next tile into other buffer
            const h8* g = (const h8*)midH + (size_t)(mt + NSPB) * 1536;
            #pragma unroll
            for (int q = 0; q < 3; q++) gl_lds16(g + q*512 + t, sB[cur^1] + q*512 + t);
        }
        #pragma unroll
        for (int i = 0; i < 2; i++)
            #pragma unroll
            for (int j = 0; j < 2; j++) acc[i][j] = (f4){0.f,0.f,0.f,0.f};

        const h8* sBc = sB[cur];
        #pragma unroll
        for (int ks = 0; ks < 3; ks++) {
            const int hs = ks*4 + quad;        // hi slot 0..11
            h8 bh[2];
            #pragma unroll
            for (int j = 0; j < 2; j++) {
                int r = wn*32 + j*16 + col;
                bh[j] = sBc[hs*128 + r];
            }
            #pragma unroll
            for (int i = 0; i < 2; i++)
                #pragma unroll
                for (int j = 0; j < 2; j++) {
                    acc[i][j] = __builtin_amdgcn_mfma_f32_16x16x32_f16(ahR[ks][i],  bh[j], acc[i][j], 0, 0, 0);
                    acc[i][j] = __builtin_amdgcn_mfma_f32_16x16x32_f16(aloR[ks][i], bh[j], acc[i][j], 0, 0, 0);
                }
        }
        // epilogue: fold into class bins
        {
            float m2[2], mx16[2], my16[2], mz16[2], bm[2]; int pc[2];
            #pragma unroll
            for (int j = 0; j < 2; j++) {
                int mm = mb + wn*32 + j*16 + col;
                float4 sq = sideQ[mm];
                m2[j] = sq.x;
                mx16[j] = 16.0f*LOG2E*sq.y; my16[j] = 16.0f*LOG2E*sq.z; mz16[j] = 16.0f*LOG2E*sq.w;
                bm[j] = -8.0f*LOG2E*(sq.y*sq.y + sq.z*sq.z + sq.w*sq.w);
                pc[j] = sideC[mm];
            }
            int seg0 = sideC[mb + wn*32];
            int seg1 = sideC[mb + wn*32 + 31];
            if (seg0 == seg1) {   // wave's 32 cols uniform class
                #pragma unroll
                for (int e = 0; e < 8; e++) {
                    int nl = wm*32 + (e>>2)*16 + quad*4 + (e&3);
                    float4 sa = sSa[nl];
                    float nn = sSb[nl];
                    float rs = 0.f;
                    #pragma unroll
                    for (int j = 0; j < 2; j++) {
                        float dot = acc[e>>2][j][e&3];
                        float tt = fmaf(dot, -2.0f*(1.0f/65536.0f), nn + m2[j]);
                        float fd = fmaxf(tt, 0.0f);
                        float c = sa.w + bm[j];
                        c = fmaf(sa.z, mz16[j], c);
                        c = fmaf(sa.y, my16[j], c);
                        c = fmaf(sa.x, mx16[j], c);
                        rs += fexp2(fmaf(fd, -(0.5f/0.09f)*LOG2E, c));
                    }
                    rs += __shfl_xor(rs, 1, 64);
                    rs += __shfl_xor(rs, 2, 64);
                    rs += __shfl_xor(rs, 4, 64);
                    rs += __shfl_xor(rs, 8, 64);
                    if (col == 0) atomicAdd(&bins[nl*21 + seg0], rs);
                }
            } else {
                // boundary: classes form contiguous [seg0,seg1] (counting sort)
                // -> masked shfl-reduce per class, ONE atomic per (quad,class).
                #pragma unroll
                for (int e = 0; e < 8; e++) {
                    int nl = wm*32 + (e>>2)*16 + quad*4 + (e&3);
                    float4 sa = sSa[nl];
                    float nn = sSb[nl];
                    float w[2];
                    #pragma unroll
                    for (int j = 0; j < 2; j++) {
                        float dot = acc[e>>2][j][e&3];
                        float tt = fmaf(dot, -2.0f*(1.0f/65536.0f), nn + m2[j]);
                        float fd = fmaxf(tt, 0.0f);
                        float c = sa.w + bm[j];
                        c = fmaf(sa.z, mz16[j], c);
                        c = fmaf(sa.y, my16[j], c);
                        c = fmaf(sa.x, mx16[j], c);
                        w[j] = fexp2(fmaf(fd, -(0.5f/0.09f)*LOG2E, c));
                    }
                    for (int cc = seg0; cc <= seg1; cc++) {
                        float rs = 0.f;
                        #pragma unroll
                        for (int j = 0; j < 2; j++) rs += (pc[j] == cc) ? w[j] : 0.f;
                        rs += __shfl_xor(rs, 1, 64);
                        rs += __shfl_xor(rs, 2, 64);
                        rs += __shfl_xor(rs, 4, 64);
                        rs += __shfl_xor(rs, 8, 64);
                        if (col == 0) atomicAdd(&bins[nl*21 + cc], rs);
                    }
                }
            }
        }
        __syncthreads();   // prefetch landed + all waves done reading sB[cur]
        cur ^= 1;
    }
    __syncthreads();
    for (int i = t; i < 64*OUT; i += 512) {
        int loc = i / OUT, k = i - loc*OUT;
        pb[((size_t)sp*N + n0 + loc)*OUT + k] = bins[loc*21 + k];
    }
}

__global__ void k_uw_final(const float* __restrict__ pb, const float* __restrict__ svp,
                           float* __restrict__ out_uw, float* __restrict__ out_spu) {
    int n = blockIdx.x * 256 + threadIdx.x;
    if (n >= N) return;
    float s[OUT];
    #pragma unroll
    for (int k = 0; k < OUT; k++) s[k] = 0.f;
    for (int sp = 0; sp < NSPB; sp++) {
        size_t base = ((size_t)sp * N + n) * OUT;
        #pragma unroll
        for (int k = 0; k < OUT; k++) s[k] += pb[base + k];
    }
    float tot = 0.f;
    #pragma unroll
    for (int k = 0; k < OUT; k++) tot += s[k];
    float rden = 1.0f / (tot + 1e-16f);
    float p[OUT]; float mx = -3.4e38f;
    #pragma unroll
    for (int k = 0; k < OUT; k++) { p[k] = svp[(size_t)n*OUT + k]; mx = fmaxf(mx, p[k]); }
    float es = 0.f;
    #pragma unroll
    for (int k = 0; k < OUT; k++) { p[k] = __expf(p[k] - mx); es += p[k]; }
    float res = 1.0f / es;
    #pragma unroll
    for (int k = 0; k < OUT; k++) {
        float uw = s[k] * rden;
        out_uw[(size_t)n*OUT + k] = uw;
        out_spu[(size_t)n*OUT + k] = 0.5f * (p[k] * res) + 0.5f * uw;
    }
}

// ---------------------------------------------------------------- scatter (fused, 1 block)
__global__ void k_scatter(const int* __restrict__ smi, const int* __restrict__ gtcls,
                          float* __restrict__ spu, int* __restrict__ pos) {
    __shared__ int sflag;
    const int t = threadIdx.x;
    if (t == 0) sflag = 0;
    __syncthreads();
    float v[2]; int idx[2];
    #pragma unroll
    for (int k = 0; k < 2; k++) {
        int i = t + k*1024;
        idx[k] = smi[i];
        v[k] = spu[(size_t)idx[k]*OUT + gtcls[i]];
        if (v[k] > 0.1f) atomicOr(&sflag, 1);
        atomicMax(&pos[idx[k]], i);
    }
    __syncthreads();
    const bool any = (sflag != 0);
    #pragma unroll
    for (int k = 0; k < 2; k++) {
        int i = t + k*1024;
        if (atomicMax(&pos[idx[k]], -1) != i) continue;   // not last writer
        bool tmp = any ? (v[k] > 0.1f) : (v[k] > 0.0f);
        if (!tmp) continue;
        int cls = gtcls[i];
        #pragma unroll
        for (int kk = 0; kk < OUT; kk++)
            spu[(size_t)idx[k]*OUT + kk] = (kk == cls) ? 1.0f : 0.0f;
    }
}

// ---------------------------------------------------------------- trust / finalize
__global__ void k_trust_pre(const float* __restrict__ spu, float* __restrict__ maxv,
                            int* __restrict__ amax, int* __restrict__ flags) {
    int n = blockIdx.x * 256 + threadIdx.x;
    if (n >= N) return;
    float best = spu[(size_t)n*OUT]; int bi = 0;
    #pragma unroll
    for (int k = 1; k < OUT; k++) {
        float v = spu[(size_t)n*OUT + k];
        if (v > best) { best = v; bi = k; }
    }
    maxv[n] = best; amax[n] = bi;
    if (best >= 0.9f) atomicOr(&flags[1], 1);
}

__global__ void k_finalize(const float* __restrict__ mf, const float* __restrict__ ori,
                           const float* __restrict__ maxv, const int* __restrict__ amax,
                           const int* __restrict__ flags,
                           float* __restrict__ out_trust, float* __restrict__ out_mf,
                           float* __restrict__ out_ori, float* __restrict__ out_pre) {
    int n = blockIdx.x * 256 + threadIdx.x;
    if (n >= N) return;
    float mv = maxv[n];
    bool tr = flags[1] ? (mv >= 0.9f) : (mv >= 0.85f);
    float m = tr ? 1.f : 0.f;
    out_trust[n] = m;
    const float4* src = (const float4*)(mf + (size_t)n * C);
    float4* dst = (float4*)(out_mf + (size_t)n * C);
    #pragma unroll
    for (int c = 0; c < 24; c++) {
        float4 v = src[c];
        v.x *= m; v.y *= m; v.z *= m; v.w *= m;
        dst[c] = v;
    }
    out_ori[n*3]   = ori[n*3]   * m;
    out_ori[n*3+1] = ori[n*3+1] * m;
    out_ori[n*3+2] = ori[n*3+2] * m;
    int bi = amax[n];
    #pragma unroll
    for (int k = 0; k < OUT; k++) out_pre[(size_t)n*OUT + k] = (k == bi) ? m : 0.f;
}

// ---------------------------------------------------------------- launch
extern "C" void kernel_launch(void* const* d_in, const int* in_sizes, int n_in,
                              void* d_out, int out_size, void* d_ws, size_t ws_size,
                              hipStream_t stream) {
    (void)in_sizes; (void)n_in; (void)out_size; (void)ws_size;
    const float* ssf     = (const float*)d_in[0];
    const float* scoords = (const float*)d_in[1];
    const float* gt      = (const float*)d_in[2];
    const float* svp     = (const float*)d_in[3];
    const float* mf      = (const float*)d_in[4];
    const float* ori     = (const float*)d_in[5];
    const float* posses  = (const float*)d_in[6];
    const int*   ran     = (const int*)d_in[7];

    float* out = (float*)d_out;
    float* out_trust = out;
    float* out_mf    = out_trust + N;
    float* out_ori   = out_mf + (size_t)N*C;
    float* out_pre   = out_ori + (size_t)N*3;
    float* out_uw    = out_pre + (size_t)N*OUT;
    float* out_spu   = out_uw  + (size_t)N*OUT;
    float* out_smi   = out_spu + (size_t)N*OUT;

    char* ws = (char*)d_ws;
    float*     w_al    = (float*)(ws + OFF_AL);
    float*     w_updf  = (float*)(ws + OFF_UPDF);
    int*       w_gtc   = (int*)(ws + OFF_GTC);
    int*       w_smi   = (int*)(ws + OFF_SMI);
    int*       w_perm  = (int*)(ws + OFF_PERM);
    _Float16*  w_aP    = (_Float16*)(ws + OFF_AP);
    _Float16*  w_bQ    = (_Float16*)(ws + OFF_BQ);
    _Float16*  w_mfP   = (_Float16*)(ws + OFF_MFP);
    _Float16*  w_midH  = (_Float16*)(ws + OFF_MIDH);
    float*     w_pav   = (float*)(ws + OFF_PAV);
    int*       w_pai   = (int*)(ws + OFF_PAI);
    float*     w_pb    = (float*)(ws + OFF_PB);
    int*       w_pos   = (int*)(ws + OFF_POS);
    float*     w_maxv  = (float*)(ws + OFF_MAXV);
    int*       w_amax  = (int*)(ws + OFF_AMAX);
    int*       w_flags = (int*)(ws + OFF_FLAGS);
    int*       w_cnt   = (int*)(ws + OFF_CNT);
    int*       w_meta  = (int*)(ws + OFF_META);
    float4*    w_nq4   = (float4*)(ws + OFF_NQ4);
    float4*    w_sideQ = (float4*)(ws + OFF_SIDEQ);
    int*       w_sideC = (int*)(ws + OFF_SIDEC);

    hipMemsetAsync(w_pos, 0xFF, (size_t)N*4, stream);   // -1
    hipMemsetAsync(w_flags, 0, 8, stream);
    hipMemsetAsync(w_cnt, 0, OUT*4, stream);

    k_prep<<<1024, 64, 0, stream>>>(ssf, scoords, gt, ran, posses, mf, ori,
                                    w_al, w_aP, w_updf, w_gtc, w_cnt,
                                    w_bQ, w_mfP, w_nq4);
    k_argmin<<<dim3(M/64, NSPA), 512, 0, stream>>>(w_aP, w_bQ, w_al, w_nq4, w_pav, w_pai);
    k_scan<<<1, 64, 0, stream>>>(w_cnt, w_meta);
    k_permute<<<M/256, 256, 0, stream>>>(w_pav, w_pai, w_gtc, w_updf, w_meta, w_perm,
                                         w_smi, out_smi);
    k_gather_sorted<<<((M+256)*12)/256, 256, 0, stream>>>(w_meta, w_perm, w_smi, w_gtc,
                                                          w_mfP, w_nq4,
                                                          w_midH, w_sideQ, w_sideC);
    k_uw<<<dim3(N/64, NSPB), 512, 0, stream>>>(w_mfP, w_midH, w_nq4,
                                               w_sideQ, w_sideC, w_meta, w_pb);
    k_uw_final<<<N/256, 256, 0, stream>>>(w_pb, svp, out_uw, out_spu);
    k_scatter<<<1, 1024, 0, stream>>>(w_smi, w_gtc, out_spu, w_pos);
    k_trust_pre<<<N/256, 256, 0, stream>>>(out_spu, w_maxv, w_amax, w_flags);
    k_finalize<<<N/256, 256, 0, stream>>>(mf, ori, w_maxv, w_amax, w_flags,
                                          out_trust, out_mf, out_ori, out_pre);
}

// Round 12
// 225.575 us; speedup vs baseline: 1.0822x; 1.0822x over previous
//
#include <hip/hip_runtime.h>
#include <math.h>

#define N 8192
#define M 8192
#define C 96
#define OUT 20
#define LG 2048

#define KP2 192     // stored K per row: [hi(96)|lo(96)] fp16, 24 h8 slots
#define NSPA 4      // y-slices pass A
#define NSPB 4      // y-slices pass B
#define LOG2E 1.4426950408889634f

typedef _Float16 h8 __attribute__((ext_vector_type(8)));
typedef float    f4 __attribute__((ext_vector_type(4)));

// native v_exp_f32 (exp2f = libm-precise __ocml call, ~10 instrs; this is 1)
__device__ __forceinline__ float fexp2(float x) { return __builtin_amdgcn_exp2f(x); }

// async global->LDS, 16B per lane, no VGPR round-trip (m97 path)
__device__ __forceinline__ void gl_lds16(const h8* g, h8* l) {
    __builtin_amdgcn_global_load_lds(
        (const __attribute__((address_space(1))) unsigned int*)g,
        (__attribute__((address_space(3))) unsigned int*)l,
        16, 0, 0);
}

// tile-slot-major h8 index: rows grouped in 128-row tiles, slot-major inside
__device__ __forceinline__ size_t tsm24(int row, int slot) {
    return ((size_t)(row >> 7) * 24 + slot) * 128 + (row & 127);
}

// ---------------- workspace layout (bytes, all 256-aligned) ----------------
constexpr size_t OFF_AL    = 256;
constexpr size_t OFF_UPDF  = OFF_AL    + (size_t)M*3*4;
constexpr size_t OFF_GTC   = OFF_UPDF  + (size_t)M*4;
constexpr size_t OFF_SMI   = OFF_GTC   + (size_t)M*4;
constexpr size_t OFF_PERM  = OFF_SMI   + (size_t)M*4;
constexpr size_t OFF_AP    = OFF_PERM  + (size_t)M*4;            // M x 192 fp16 (tsm24)
constexpr size_t OFF_BQ    = OFF_AP    + (size_t)M*KP2*2;        // N x 192 fp16
constexpr size_t OFF_MFP   = OFF_BQ    + (size_t)N*KP2*2;        // N x 192 fp16
constexpr size_t OFF_MIDH  = OFF_MFP   + (size_t)N*KP2*2;        // (M+256) x 12 hi slots
constexpr size_t OFF_PAV   = OFF_MIDH  + (size_t)(M+256)*192;    // NSPA x M
constexpr size_t OFF_PAI   = OFF_PAV   + (size_t)NSPA*M*4;
constexpr size_t OFF_PB    = OFF_PAI   + (size_t)NSPA*M*4;       // NSPB x N x 20
constexpr size_t OFF_POS   = OFF_PB    + (size_t)NSPB*N*OUT*4;
constexpr size_t OFF_MAXV  = OFF_POS   + (size_t)N*4;
constexpr size_t OFF_AMAX  = OFF_MAXV  + (size_t)N*4;
constexpr size_t OFF_FLAGS = OFF_AMAX  + (size_t)N*4;            // 256 B
constexpr size_t OFF_CNT   = OFF_FLAGS + 256;                    // 256 B (zeroed w/ flags)
constexpr size_t OFF_CUR   = OFF_CNT   + 256;                    // 256 B (zeroed w/ flags)
constexpr size_t OFF_NQ4   = OFF_CUR   + 256;                    // N x float4 {ox,oy,oz,nmf2}
constexpr size_t OFF_SIDEQ = OFF_NQ4   + (size_t)N*16;           // (M+256) x float4 {m2,mx,my,mz}
constexpr size_t OFF_SIDEC = OFF_SIDEQ + (size_t)(M+256)*16;     // (M+256) int cls

// ---------------------------------------------------------------- fused prep
// 512 blocks x 64 threads: blocks [0,256) m-side (inline 4x4 inverse + class
// hist), blocks [256,512) n-side (+ pos=-1 init, replacing a 32 KB memset).
__global__ void k_prep(const float* __restrict__ ssf, const float* __restrict__ scoords,
                       const float* __restrict__ gt, const int* __restrict__ ran_mask,
                       const float* __restrict__ posses,
                       const float* __restrict__ mf, const float* __restrict__ ori,
                       float* __restrict__ al, _Float16* __restrict__ aP,
                       float* __restrict__ updf, int* __restrict__ gtcls,
                       int* __restrict__ cnt,
                       _Float16* __restrict__ bQ, _Float16* __restrict__ mfP,
                       float4* __restrict__ nq4, int* __restrict__ pos) {
    const int tt = threadIdx.x;          // 0..63
    if (blockIdx.x < 256) {
        // ---------------- m-side ----------------
        __shared__ int hcnt[OUT];
        __shared__ float sdiff[12];
        if (tt == 0) {   // inline inv(posses[1]) @ posses[0], rows 0..2
            float a[4][8];
            for (int i = 0; i < 4; i++)
                for (int j = 0; j < 4; j++) {
                    a[i][j]     = posses[16 + i*4 + j];
                    a[i][4 + j] = (i == j) ? 1.f : 0.f;
                }
            for (int col = 0; col < 4; col++) {
                int piv = col; float mx = fabsf(a[col][col]);
                for (int r = col + 1; r < 4; r++) {
                    float v = fabsf(a[r][col]);
                    if (v > mx) { mx = v; piv = r; }
                }
                if (piv != col)
                    for (int j = 0; j < 8; j++) { float t2 = a[col][j]; a[col][j] = a[piv][j]; a[piv][j] = t2; }
                float inv = 1.0f / a[col][col];
                for (int j = 0; j < 8; j++) a[col][j] *= inv;
                for (int r = 0; r < 4; r++) {
                    if (r == col) continue;
                    float f = a[r][col];
                    for (int j = 0; j < 8; j++) a[r][j] -= f * a[col][j];
                }
            }
            for (int i = 0; i < 3; i++)
                for (int j = 0; j < 4; j++) {
                    float s2 = 0.f;
                    for (int k = 0; k < 4; k++) s2 += a[i][4 + k] * posses[k*4 + j];
                    sdiff[i*4 + j] = s2;
                }
        }
        if (tt < OUT) hcnt[tt] = 0;
        __syncthreads();
        const int m = blockIdx.x * 32 + (tt >> 1);
        const int h = tt & 1;
        const float4* r4 = (const float4*)(ssf + (size_t)m * C);
        float4 row[12]; float s = 0.f;
        #pragma unroll
        for (int c = 0; c < 12; c++) {
            float4 v = r4[h*12 + c];
            row[c] = v;
            s += v.x*v.x + v.y*v.y + v.z*v.z + v.w*v.w;
        }
        s += __shfl_xor(s, 1, 64);
        float scale = 256.0f / sqrtf(s);
        h8* dst = (h8*)aP;
        #pragma unroll
        for (int qq = 0; qq < 6; qq++) {
            int q = h*6 + qq;
            float4 u = row[2*qq], v = row[2*qq+1];
            float xs[8] = {u.x,u.y,u.z,u.w,v.x,v.y,v.z,v.w};
            h8 hi, lo;
            #pragma unroll
            for (int e = 0; e < 8; e++) {
                float xv = xs[e] * scale;
                _Float16 hh = (_Float16)xv;
                hi[e] = hh;
                lo[e] = (_Float16)(xv - (float)hh);
            }
            dst[tsm24(m, q)]      = hi;
            dst[tsm24(m, 12 + q)] = lo;
        }
        if (h == 0) {
            float x = scoords[m*3], y = scoords[m*3+1], z = scoords[m*3+2];
            #pragma unroll
            for (int j = 0; j < 3; j++)
                al[m*3 + j] = sdiff[j*4+0]*x + sdiff[j*4+1]*y + sdiff[j*4+2]*z + sdiff[j*4+3];
            int best = 0; float bv = gt[(size_t)m*OUT];
            #pragma unroll
            for (int k = 1; k < OUT; k++) {
                float v = gt[(size_t)m*OUT + k];
                if (v > bv) { bv = v; best = k; }
            }
            gtcls[m] = best;
            bool upd = (best < 9 || m < LG || ran_mask[m] == 1);
            updf[m] = upd ? 1.f : 0.f;
            if (upd) atomicAdd(&hcnt[best], 1);
        }
        __syncthreads();
        if (tt < OUT) atomicAdd(&cnt[tt], hcnt[tt]);
    } else {
        // ---------------- n-side ----------------
        const int bb = blockIdx.x - 256;
        if (tt < 32) pos[bb*32 + tt] = -1;        // replaces pos memset
        const int n = bb * 32 + (tt >> 1);
        const int h = tt & 1;
        const float4* r4 = (const float4*)(mf + (size_t)n * C);
        float4 row[12]; float s = 0.f;
        #pragma unroll
        for (int c = 0; c < 12; c++) {
            float4 v = r4[h*12 + c];
            row[c] = v;
            s += v.x*v.x + v.y*v.y + v.z*v.z + v.w*v.w;
        }
        s += __shfl_xor(s, 1, 64);
        if (h == 0) {
            float4 o;
            o.x = ori[n*3]; o.y = ori[n*3+1]; o.z = ori[n*3+2]; o.w = s;
            nq4[n] = o;
        }
        float scn = 256.0f / sqrtf(s);
        h8* dB = (h8*)bQ;
        h8* dF = (h8*)mfP;
        #pragma unroll
        for (int qq = 0; qq < 6; qq++) {
            int q = h*6 + qq;
            float4 u = row[2*qq], v = row[2*qq+1];
            float xs[8] = {u.x,u.y,u.z,u.w,v.x,v.y,v.z,v.w};
            h8 hiN, loN, hiF, loF;
            #pragma unroll
            for (int e = 0; e < 8; e++) {
                float xn = xs[e] * scn;
                _Float16 hn = (_Float16)xn;
                hiN[e] = hn; loN[e] = (_Float16)(xn - (float)hn);
                float xf = xs[e] * 256.0f;
                _Float16 hf = (_Float16)xf;
                hiF[e] = hf; loF[e] = (_Float16)(xf - (float)hf);
            }
            dB[tsm24(n, q)]    = hiN;
            dB[tsm24(n, 12+q)] = loN;
            dF[tsm24(n, q)]    = hiF;
            dF[tsm24(n, 12+q)] = loF;
        }
    }
}

// ---------------------------------------------------------------- pass A: MFMA argmin
// EXACT round-9 version (best measured: 56.0 us). 1024 threads, 128m resident
// (fragments hoisted to registers), 128-col double-buffered B tiles, native exp2.
__global__ __launch_bounds__(1024, 1) void k_argmin(
        const _Float16* __restrict__ aP, const _Float16* __restrict__ bQ,
        const float* __restrict__ al, const float4* __restrict__ nq4,
        float* __restrict__ pav, int* __restrict__ pai) {
    __shared__ h8 sA[24*128];          // 48 KB resident full-K
    __shared__ h8 sB[2][24*128];       // 2 x 48 KB streamed (128 n-cols/tile)
    __shared__ float xv[4*128];
    __shared__ int   xi[4*128];
    __shared__ float4 sMs[128];        // {4axL,4ayL,4azL,-2|a|^2 L} per m-row
    const int t = threadIdx.x;
    const int wave = t >> 6, lane = t & 63;
    const int col = lane & 15, quad = lane >> 4;
    const int wm = wave >> 2, wn = wave & 3;     // 4m x 4n
    const int m0 = blockIdx.x * 128;
    const int sp = blockIdx.y;

    {   // stage resident A + first streamed tile async
        const h8* gA = (const h8*)aP + (size_t)blockIdx.x * 3072;
        #pragma unroll
        for (int q = 0; q < 3; q++) gl_lds16(gA + q*1024 + t, sA + q*1024 + t);
        const h8* g = (const h8*)bQ + (size_t)sp * 3072;
        #pragma unroll
        for (int q = 0; q < 3; q++) gl_lds16(g + q*1024 + t, sB[0] + q*1024 + t);
    }
    if (t < 128) {   // per-m expanded terms into LDS (log2e pre-folded)
        float ax = al[(m0+t)*3+0], ay = al[(m0+t)*3+1], az = al[(m0+t)*3+2];
        sMs[t] = (float4){4.0f*LOG2E*ax, 4.0f*LOG2E*ay, 4.0f*LOG2E*az,
                          -2.0f*LOG2E*(ax*ax+ay*ay+az*az)};
    }
    float best[8]; int bidx[8];
    #pragma unroll
    for (int e = 0; e < 8; e++) { best[e] = 3.4e38f; bidx[e] = 0; }

    __syncthreads();                       // sA + sB[0] + sMs visible

    // hoist resident-A fragments to registers (loop-invariant): 48 VGPR
    h8 ahR[3][2], aloR[3][2];
    #pragma unroll
    for (int ks = 0; ks < 3; ks++) {
        const int hs = ks*4 + quad;
        #pragma unroll
        for (int i = 0; i < 2; i++) {
            int ml = wm*32 + i*16 + col;
            ahR[ks][i]  = sA[hs*128 + ml];
            aloR[ks][i] = sA[(12+hs)*128 + ml];
        }
    }

    const int NT = (N/128) / NSPA;         // 16 tiles per slice
    int cur = 0;
    f4 acc[2][2];
    for (int u = 0; u < NT; u++) {
        const int tile = sp + u*NSPA;
        if (u + 1 < NT) {                  // prefetch next tile into other buffer
            const h8* g = (const h8*)bQ + (size_t)(sp + (u+1)*NSPA) * 3072;
            #pragma unroll
            for (int q = 0; q < 3; q++) gl_lds16(g + q*1024 + t, sB[cur^1] + q*1024 + t);
        }
        #pragma unroll
        for (int i = 0; i < 2; i++)
            #pragma unroll
            for (int j = 0; j < 2; j++) acc[i][j] = (f4){0.f,0.f,0.f,0.f};

        const h8* sBc = sB[cur];
        #pragma unroll
        for (int ks = 0; ks < 3; ks++) {
            const int hs = ks*4 + quad;        // hi slot; lo slot = 12+hs
            h8 bh[2], blo[2];
            #pragma unroll
            for (int j = 0; j < 2; j++) {
                int r = wn*32 + j*16 + col;
                bh[j]  = sBc[hs*128 + r];
                blo[j] = sBc[(12+hs)*128 + r];
            }
            #pragma unroll
            for (int i = 0; i < 2; i++)
                #pragma unroll
                for (int j = 0; j < 2; j++) {
                    acc[i][j] = __builtin_amdgcn_mfma_f32_16x16x32_f16(ahR[ks][i],  bh[j],  acc[i][j], 0, 0, 0);
                    acc[i][j] = __builtin_amdgcn_mfma_f32_16x16x32_f16(ahR[ks][i],  blo[j], acc[i][j], 0, 0, 0);
                    acc[i][j] = __builtin_amdgcn_mfma_f32_16x16x32_f16(aloR[ks][i], bh[j],  acc[i][j], 0, 0, 0);
                }
        }
        // epilogue: running per-lane argmin (e-outer, native exp2)
        const int n0t = tile * 128;
        float4 o4[2]; float bn[2]; int nidx[2];
        #pragma unroll
        for (int j = 0; j < 2; j++) {
            nidx[j] = n0t + wn*32 + j*16 + col;
            o4[j] = nq4[nidx[j]];
            bn[j] = -2.0f*LOG2E*(o4[j].x*o4[j].x + o4[j].y*o4[j].y + o4[j].z*o4[j].z);
        }
        #pragma unroll
        for (int e = 0; e < 8; e++) {
            int ml = wm*32 + (e>>2)*16 + quad*4 + (e&3);
            float4 sm = sMs[ml];
            #pragma unroll
            for (int j = 0; j < 2; j++) {
                float dot = acc[e>>2][j][e&3];
                float c = sm.w + bn[j];
                c = fmaf(sm.z, o4[j].z, c);
                c = fmaf(sm.y, o4[j].y, c);
                c = fmaf(sm.x, o4[j].x, c);
                float sim = fmaf(dot, -(1.0f/65536.0f), 2.0f) - fexp2(c);
                if (sim < best[e]) { best[e] = sim; bidx[e] = nidx[j]; }
            }
        }
        __syncthreads();      // prefetch landed + all waves done reading sB[cur]
        cur ^= 1;
    }
    // butterfly over 16 col-lanes, once per block
    #pragma unroll
    for (int e = 0; e < 8; e++) {
        float bv = best[e]; int bi = bidx[e];
        #pragma unroll
        for (int d = 1; d < 16; d <<= 1) {
            float ov = __shfl_xor(bv, d, 64);
            int   oi = __shfl_xor(bi, d, 64);
            if (ov < bv || (ov == bv && oi < bi)) { bv = ov; bi = oi; }
        }
        best[e] = bv; bidx[e] = bi;
    }
    if (col == 0) {
        #pragma unroll
        for (int e = 0; e < 8; e++) {
            int ml = wm*32 + (e>>2)*16 + quad*4 + (e&3);
            xv[wn*128 + ml] = best[e];
            xi[wn*128 + ml] = bidx[e];
        }
    }
    __syncthreads();
    if (t < 128) {   // single writer per (sp, m)
        float bv = xv[t]; int bi = xi[t];
        #pragma unroll
        for (int w = 1; w < 4; w++) {
            float v = xv[w*128 + t]; int i2 = xi[w*128 + t];
            if (v < bv || (v == bv && i2 < bi)) { bv = v; bi = i2; }
        }
        pav[(size_t)sp * M + m0 + t] = bv;
        pai[(size_t)sp * M + m0 + t] = bi;
    }
}

// ---------------------------------------------------------------- permute
// Counting-sort placement with per-thread redundant prefix from cnt (k_scan
// deleted); cursor[] zeroed by the single memset. Also folds the 4-way
// argmin reduce (same M-indexed grid).
__global__ void k_permute(const float* __restrict__ pav, const int* __restrict__ pai,
                          const int* __restrict__ gtcls, const float* __restrict__ updf,
                          const int* __restrict__ cnt, int* __restrict__ cursor,
                          int* __restrict__ perm,
                          int* __restrict__ smi, float* __restrict__ out_smi) {
    int m = blockIdx.x * 256 + threadIdx.x;
    if (m >= M) return;
    float best = 3.4e38f; int bidx = 0;
    for (int sp = 0; sp < NSPA; sp++) {
        float v = pav[(size_t)sp * M + m];
        int   i = pai[(size_t)sp * M + m];
        if (v < best || (v == best && i < bidx)) { best = v; bidx = i; }
    }
    smi[m] = bidx;
    out_smi[m] = (float)bidx;
    if (updf[m] == 0.f) return;
    int cls = gtcls[m];
    int base = 0;
    #pragma unroll
    for (int k = 0; k < OUT; k++) base += (k < cls) ? cnt[k] : 0;
    int p = base + atomicAdd(&cursor[cls], 1);
    perm[p] = m;
}

// gather sorted+compacted mid rows, HI SLOTS ONLY (12/row) into compact midH;
// packs per-row side data {m2,mx,my,mz} + cls for k_uw. mact derived from cnt.
__global__ void k_gather_sorted(const int* __restrict__ cnt, const int* __restrict__ perm,
                                const int* __restrict__ smi, const int* __restrict__ gtcls,
                                const _Float16* __restrict__ mfP, const float4* __restrict__ nq4,
                                _Float16* __restrict__ midH,
                                float4* __restrict__ sideQ, int* __restrict__ sideC) {
    __shared__ int smact;
    if (threadIdx.x == 0) {
        int s = 0;
        #pragma unroll
        for (int k = 0; k < OUT; k++) s += cnt[k];
        smact = s;
    }
    __syncthreads();
    int mact = smact;
    int mpad = ((mact + 255) >> 8) << 8;
    int tid = blockIdx.x * 256 + threadIdx.x;
    int rr = tid / 12;
    int q  = tid - rr * 12;          // hi slot 0..11
    if (rr >= mpad) return;
    h8* dst = (h8*)midH;
    size_t didx = ((size_t)(rr >> 7) * 12 + q) * 128 + (rr & 127);
    if (rr < mact) {
        int m = perm[rr];
        int s = smi[m];
        dst[didx] = ((const h8*)mfP)[tsm24(s, q)];
        if (q == 0) {
            float4 o = nq4[s];
            float4 sq;
            sq.x = o.w;                       // |feat|^2
            sq.y = o.x; sq.z = o.y; sq.w = o.z;
            sideQ[rr] = sq;
            sideC[rr] = gtcls[m];
        }
    } else {
        dst[didx] = (h8)(_Float16)0.f;
        if (q == 0) {
            sideQ[rr] = (float4){1e9f, 0.f, 0.f, 0.f};   // fd=1e9 -> w = 0 exactly
            sideC[rr] = 0;
        }
    }
}

// ---------------------------------------------------------------- pass B: MFMA class-binned sums
// EXACT round-9 version (hi-only B, 256-col dbuf tiles, hoisted resident
// fragments, boundary masked class-range reduce, native exp2); nmac derived
// from cnt (meta deleted).
__global__ __launch_bounds__(1024, 1) void k_uw(
        const _Float16* __restrict__ mfP, const _Float16* __restrict__ midH,
        const float4* __restrict__ nq4,
        const float4* __restrict__ sideQ, const int* __restrict__ sideC,
        const int* __restrict__ cnt, float* __restrict__ pb) {
    __shared__ h8 sN[24*128];          // 48 KB resident n-rows (hi+lo)
    __shared__ h8 sB[2][2*12*128];     // 2 x 48 KB streamed mid tiles (hi only, 256 cols)
    __shared__ float bins[128*21];
    __shared__ float4 sSa[128];        // {ox,oy,oz,-8L|o|^2} per n-row
    __shared__ float  sSb[128];        // nmf2 per n-row
    __shared__ int    snmac;
    const int t = threadIdx.x;
    const int wave = t >> 6, lane = t & 63;
    const int col = lane & 15, quad = lane >> 4;
    const int wm = wave >> 2, wn = wave & 3;     // 4m x 4n
    const int n0 = blockIdx.x * 128;
    const int sp = blockIdx.y;

    if (t == 0) {
        int s = 0;
        #pragma unroll
        for (int k = 0; k < OUT; k++) s += cnt[k];
        snmac = (s + 255) >> 8;
    }
    __syncthreads();
    const int nmac = snmac;

    {   // stage resident n-rows + first streamed tile async
        const h8* gN = (const h8*)mfP + (size_t)blockIdx.x * 3072;
        #pragma unroll
        for (int q = 0; q < 3; q++) gl_lds16(gN + q*1024 + t, sN + q*1024 + t);
        if (sp < nmac) {
            const h8* g = (const h8*)midH + (size_t)(2*sp) * 1536;
            #pragma unroll
            for (int q = 0; q < 3; q++) gl_lds16(g + q*1024 + t, sB[0] + q*1024 + t);
        }
    }
    if (t < 128) {   // per-n expanded terms into LDS (log2e pre-folded)
        float4 q = nq4[n0 + t];
        sSa[t] = (float4){q.x, q.y, q.z, -8.0f*LOG2E*(q.x*q.x + q.y*q.y + q.z*q.z)};
        sSb[t] = q.w;
    }
    for (int i = t; i < 128*21; i += 1024) bins[i] = 0.f;

    __syncthreads();                   // sN + sB[0] + side + bins visible

    // hoist resident-N fragments to registers (loop-invariant): 48 VGPR
    h8 ahR[3][2], aloR[3][2];
    #pragma unroll
    for (int ks = 0; ks < 3; ks++) {
        const int hs = ks*4 + quad;
        #pragma unroll
        for (int i = 0; i < 2; i++) {
            int ml = wm*32 + i*16 + col;
            ahR[ks][i]  = sN[hs*128 + ml];
            aloR[ks][i] = sN[(12+hs)*128 + ml];
        }
    }

    int cur = 0;
    f4 acc[2][4];
    for (int mt = sp; mt < nmac; mt += NSPB) {
        const int mb = mt * 256;
        if (mt + NSPB < nmac) {        // prefetch next tile into other buffer
            const h8* g = (const h8*)midH + (size_t)(2*(mt + NSPB)) * 1536;
            #pragma unroll
            for (int q = 0; q < 3; q++) gl_lds16(g + q*1024 + t, sB[cur^1] + q*1024 + t);
        }
        #pragma unroll
        for (int i = 0; i < 2; i++)
            #pragma unroll
            for (int j = 0; j < 4; j++) acc[i][j] = (f4){0.f,0.f,0.f,0.f};

        const h8* sBc = sB[cur];
        #pragma unroll
        for (int ks = 0; ks < 3; ks++) {
            const int hs = ks*4 + quad;        // hi slot 0..11
            h8 bh[4];
            #pragma unroll
            for (int j = 0; j < 4; j++) {
                int r = wn*64 + j*16 + col;
                int tb = (r >> 7) * 1536, rl = r & 127;
                bh[j]  = sBc[tb + hs*128 + rl];
            }
            #pragma unroll
            for (int i = 0; i < 2; i++)
                #pragma unroll
                for (int j = 0; j < 4; j++) {
                    acc[i][j] = __builtin_amdgcn_mfma_f32_16x16x32_f16(ahR[ks][i],  bh[j], acc[i][j], 0, 0, 0);
                    acc[i][j] = __builtin_amdgcn_mfma_f32_16x16x32_f16(aloR[ks][i], bh[j], acc[i][j], 0, 0, 0);
                }
        }
        // epilogue: fold into class bins
        {
            float m2[4], mx16[4], my16[4], mz16[4], bm[4]; int pc[4];
            #pragma unroll
            for (int j = 0; j < 4; j++) {
                int mm = mb + wn*64 + j*16 + col;
                float4 sq = sideQ[mm];
                m2[j] = sq.x;
                mx16[j] = 16.0f*LOG2E*sq.y; my16[j] = 16.0f*LOG2E*sq.z; mz16[j] = 16.0f*LOG2E*sq.w;
                bm[j] = -8.0f*LOG2E*(sq.y*sq.y + sq.z*sq.z + sq.w*sq.w);
                pc[j] = sideC[mm];
            }
            int seg0 = sideC[mb + wn*64];
            int seg1 = sideC[mb + wn*64 + 63];
            if (seg0 == seg1) {   // wave's 64 cols uniform class
                #pragma unroll
                for (int e = 0; e < 8; e++) {
                    int nl = wm*32 + (e>>2)*16 + quad*4 + (e&3);
                    float4 sa = sSa[nl];
                    float nn = sSb[nl];
                    float rs = 0.f;
                    #pragma unroll
                    for (int j = 0; j < 4; j++) {
                        float dot = acc[e>>2][j][e&3];
                        float tt = fmaf(dot, -2.0f*(1.0f/65536.0f), nn + m2[j]);
                        float fd = fmaxf(tt, 0.0f);
                        float c = sa.w + bm[j];
                        c = fmaf(sa.z, mz16[j], c);
                        c = fmaf(sa.y, my16[j], c);
                        c = fmaf(sa.x, mx16[j], c);
                        rs += fexp2(fmaf(fd, -(0.5f/0.09f)*LOG2E, c));
                    }
                    rs += __shfl_xor(rs, 1, 64);
                    rs += __shfl_xor(rs, 2, 64);
                    rs += __shfl_xor(rs, 4, 64);
                    rs += __shfl_xor(rs, 8, 64);
                    if (col == 0) atomicAdd(&bins[nl*21 + seg0], rs);
                }
            } else {
                // boundary: classes form contiguous [seg0,seg1] (counting sort)
                // -> masked shfl-reduce per class, ONE atomic per (quad,class).
                #pragma unroll
                for (int e = 0; e < 8; e++) {
                    int nl = wm*32 + (e>>2)*16 + quad*4 + (e&3);
                    float4 sa = sSa[nl];
                    float nn = sSb[nl];
                    float w[4];
                    #pragma unroll
                    for (int j = 0; j < 4; j++) {
                        float dot = acc[e>>2][j][e&3];
                        float tt = fmaf(dot, -2.0f*(1.0f/65536.0f), nn + m2[j]);
                        float fd = fmaxf(tt, 0.0f);
                        float c = sa.w + bm[j];
                        c = fmaf(sa.z, mz16[j], c);
                        c = fmaf(sa.y, my16[j], c);
                        c = fmaf(sa.x, mx16[j], c);
                        w[j] = fexp2(fmaf(fd, -(0.5f/0.09f)*LOG2E, c));
                    }
                    for (int cc = seg0; cc <= seg1; cc++) {
                        float rs = 0.f;
                        #pragma unroll
                        for (int j = 0; j < 4; j++) rs += (pc[j] == cc) ? w[j] : 0.f;
                        rs += __shfl_xor(rs, 1, 64);
                        rs += __shfl_xor(rs, 2, 64);
                        rs += __shfl_xor(rs, 4, 64);
                        rs += __shfl_xor(rs, 8, 64);
                        if (col == 0) atomicAdd(&bins[nl*21 + cc], rs);
                    }
                }
            }
        }
        __syncthreads();   // prefetch landed + all waves done reading sB[cur]
        cur ^= 1;
    }
    __syncthreads();
    for (int i = t; i < 128*OUT; i += 1024) {
        int loc = i / OUT, k = i - loc*OUT;
        pb[((size_t)sp*N + n0 + loc)*OUT + k] = bins[loc*21 + k];
    }
}

__global__ void k_uw_final(const float* __restrict__ pb, const float* __restrict__ svp,
                           float* __restrict__ out_uw, float* __restrict__ out_spu) {
    int n = blockIdx.x * 256 + threadIdx.x;
    if (n >= N) return;
    float s[OUT];
    #pragma unroll
    for (int k = 0; k < OUT; k++) s[k] = 0.f;
    for (int sp = 0; sp < NSPB; sp++) {
        size_t base = ((size_t)sp * N + n) * OUT;
        #pragma unroll
        for (int k = 0; k < OUT; k++) s[k] += pb[base + k];
    }
    float tot = 0.f;
    #pragma unroll
    for (int k = 0; k < OUT; k++) tot += s[k];
    float rden = 1.0f / (tot + 1e-16f);
    float p[OUT]; float mx = -3.4e38f;
    #pragma unroll
    for (int k = 0; k < OUT; k++) { p[k] = svp[(size_t)n*OUT + k]; mx = fmaxf(mx, p[k]); }
    float es = 0.f;
    #pragma unroll
    for (int k = 0; k < OUT; k++) { p[k] = __expf(p[k] - mx); es += p[k]; }
    float res = 1.0f / es;
    #pragma unroll
    for (int k = 0; k < OUT; k++) {
        float uw = s[k] * rden;
        out_uw[(size_t)n*OUT + k] = uw;
        out_spu[(size_t)n*OUT + k] = 0.5f * (p[k] * res) + 0.5f * uw;
    }
}

// ---------------------------------------------------------------- scatter (fused, 1 block)
__global__ void k_scatter(const int* __restrict__ smi, const int* __restrict__ gtcls,
                          float* __restrict__ spu, int* __restrict__ pos) {
    __shared__ int sflag;
    const int t = threadIdx.x;
    if (t == 0) sflag = 0;
    __syncthreads();
    float v[2]; int idx[2];
    #pragma unroll
    for (int k = 0; k < 2; k++) {
        int i = t + k*1024;
        idx[k] = smi[i];
        v[k] = spu[(size_t)idx[k]*OUT + gtcls[i]];
        if (v[k] > 0.1f) atomicOr(&sflag, 1);
        atomicMax(&pos[idx[k]], i);
    }
    __syncthreads();
    const bool any = (sflag != 0);
    #pragma unroll
    for (int k = 0; k < 2; k++) {
        int i = t + k*1024;
        if (atomicMax(&pos[idx[k]], -1) != i) continue;   // not last writer
        bool tmp = any ? (v[k] > 0.1f) : (v[k] > 0.0f);
        if (!tmp) continue;
        int cls = gtcls[i];
        #pragma unroll
        for (int kk = 0; kk < OUT; kk++)
            spu[(size_t)idx[k]*OUT + kk] = (kk == cls) ? 1.0f : 0.0f;
    }
}

// ---------------------------------------------------------------- trust / finalize
__global__ void k_trust_pre(const float* __restrict__ spu, float* __restrict__ maxv,
                            int* __restrict__ amax, int* __restrict__ flags) {
    int n = blockIdx.x * 256 + threadIdx.x;
    if (n >= N) return;
    float best = spu[(size_t)n*OUT]; int bi = 0;
    #pragma unroll
    for (int k = 1; k < OUT; k++) {
        float v = spu[(size_t)n*OUT + k];
        if (v > best) { best = v; bi = k; }
    }
    maxv[n] = best; amax[n] = bi;
    if (best >= 0.9f) atomicOr(&flags[1], 1);
}

__global__ void k_finalize(const float* __restrict__ mf, const float* __restrict__ ori,
                           const float* __restrict__ maxv, const int* __restrict__ amax,
                           const int* __restrict__ flags,
                           float* __restrict__ out_trust, float* __restrict__ out_mf,
                           float* __restrict__ out_ori, float* __restrict__ out_pre) {
    int n = blockIdx.x * 256 + threadIdx.x;
    if (n >= N) return;
    float mv = maxv[n];
    bool tr = flags[1] ? (mv >= 0.9f) : (mv >= 0.85f);
    float m = tr ? 1.f : 0.f;
    out_trust[n] = m;
    const float4* src = (const float4*)(mf + (size_t)n * C);
    float4* dst = (float4*)(out_mf + (size_t)n * C);
    #pragma unroll
    for (int c = 0; c < 24; c++) {
        float4 v = src[c];
        v.x *= m; v.y *= m; v.z *= m; v.w *= m;
        dst[c] = v;
    }
    out_ori[n*3]   = ori[n*3]   * m;
    out_ori[n*3+1] = ori[n*3+1] * m;
    out_ori[n*3+2] = ori[n*3+2] * m;
    int bi = amax[n];
    #pragma unroll
    for (int k = 0; k < OUT; k++) out_pre[(size_t)n*OUT + k] = (k == bi) ? m : 0.f;
}

// ---------------------------------------------------------------- launch
extern "C" void kernel_launch(void* const* d_in, const int* in_sizes, int n_in,
                              void* d_out, int out_size, void* d_ws, size_t ws_size,
                              hipStream_t stream) {
    (void)in_sizes; (void)n_in; (void)out_size; (void)ws_size;
    const float* ssf     = (const float*)d_in[0];
    const float* scoords = (const float*)d_in[1];
    const float* gt      = (const float*)d_in[2];
    const float* svp     = (const float*)d_in[3];
    const float* mf      = (const float*)d_in[4];
    const float* ori     = (const float*)d_in[5];
    const float* posses  = (const float*)d_in[6];
    const int*   ran     = (const int*)d_in[7];

    float* out = (float*)d_out;
    float* out_trust = out;
    float* out_mf    = out_trust + N;
    float* out_ori   = out_mf + (size_t)N*C;
    float* out_pre   = out_ori + (size_t)N*3;
    float* out_uw    = out_pre + (size_t)N*OUT;
    float* out_spu   = out_uw  + (size_t)N*OUT;
    float* out_smi   = out_spu + (size_t)N*OUT;

    char* ws = (char*)d_ws;
    float*     w_al    = (float*)(ws + OFF_AL);
    float*     w_updf  = (float*)(ws + OFF_UPDF);
    int*       w_gtc   = (int*)(ws + OFF_GTC);
    int*       w_smi   = (int*)(ws + OFF_SMI);
    int*       w_perm  = (int*)(ws + OFF_PERM);
    _Float16*  w_aP    = (_Float16*)(ws + OFF_AP);
    _Float16*  w_bQ    = (_Float16*)(ws + OFF_BQ);
    _Float16*  w_mfP   = (_Float16*)(ws + OFF_MFP);
    _Float16*  w_midH  = (_Float16*)(ws + OFF_MIDH);
    float*     w_pav   = (float*)(ws + OFF_PAV);
    int*       w_pai   = (int*)(ws + OFF_PAI);
    float*     w_pb    = (float*)(ws + OFF_PB);
    int*       w_pos   = (int*)(ws + OFF_POS);
    float*     w_maxv  = (float*)(ws + OFF_MAXV);
    int*       w_amax  = (int*)(ws + OFF_AMAX);
    int*       w_flags = (int*)(ws + OFF_FLAGS);
    int*       w_cnt   = (int*)(ws + OFF_CNT);
    int*       w_cur   = (int*)(ws + OFF_CUR);
    float4*    w_nq4   = (float4*)(ws + OFF_NQ4);
    float4*    w_sideQ = (float4*)(ws + OFF_SIDEQ);
    int*       w_sideC = (int*)(ws + OFF_SIDEC);

    // single memset: flags (256) + cnt (256) + cursor (256), contiguous
    hipMemsetAsync(w_flags, 0, 768, stream);

    k_prep<<<512, 64, 0, stream>>>(ssf, scoords, gt, ran, posses, mf, ori,
                                   w_al, w_aP, w_updf, w_gtc, w_cnt,
                                   w_bQ, w_mfP, w_nq4, w_pos);
    k_argmin<<<dim3(M/128, NSPA), 1024, 0, stream>>>(w_aP, w_bQ, w_al, w_nq4, w_pav, w_pai);
    k_permute<<<M/256, 256, 0, stream>>>(w_pav, w_pai, w_gtc, w_updf, w_cnt, w_cur,
                                         w_perm, w_smi, out_smi);
    k_gather_sorted<<<((M+256)*12)/256, 256, 0, stream>>>(w_cnt, w_perm, w_smi, w_gtc,
                                                          w_mfP, w_nq4,
                                                          w_midH, w_sideQ, w_sideC);
    k_uw<<<dim3(N/128, NSPB), 1024, 0, stream>>>(w_mfP, w_midH, w_nq4,
                                                 w_sideQ, w_sideC, w_cnt, w_pb);
    k_uw_final<<<N/256, 256, 0, stream>>>(w_pb, svp, out_uw, out_spu);
    k_scatter<<<1, 1024, 0, stream>>>(w_smi, w_gtc, out_spu, w_pos);
    k_trust_pre<<<N/256, 256, 0, stream>>>(out_spu, w_maxv, w_amax, w_flags);
    k_finalize<<<N/256, 256, 0, stream>>>(mf, ori, w_maxv, w_amax, w_flags,
                                          out_trust, out_mf, out_ori, out_pre);
}

// Round 13
// 223.122 us; speedup vs baseline: 1.0941x; 1.0110x over previous
//
#include <hip/hip_runtime.h>
#include <math.h>

#define N 8192
#define M 8192
#define C 96
#define OUT 20
#define LG 2048

#define KP2 192     // stored K per row: [hi(96)|lo(96)] fp16, 24 h8 slots
#define NSPA 4      // y-slices pass A
#define NSPB 4      // y-slices pass B
#define LOG2E 1.4426950408889634f

typedef _Float16 h8 __attribute__((ext_vector_type(8)));
typedef float    f4 __attribute__((ext_vector_type(4)));

// native v_exp_f32 (exp2f = libm-precise __ocml call, ~10 instrs; this is 1)
__device__ __forceinline__ float fexp2(float x) { return __builtin_amdgcn_exp2f(x); }

// async global->LDS, 16B per lane, no VGPR round-trip (m97 path)
__device__ __forceinline__ void gl_lds16(const h8* g, h8* l) {
    __builtin_amdgcn_global_load_lds(
        (const __attribute__((address_space(1))) unsigned int*)g,
        (__attribute__((address_space(3))) unsigned int*)l,
        16, 0, 0);
}

// tile-slot-major h8 index: rows grouped in 128-row tiles, slot-major inside
__device__ __forceinline__ size_t tsm24(int row, int slot) {
    return ((size_t)(row >> 7) * 24 + slot) * 128 + (row & 127);
}

// ---------------- workspace layout (bytes, all 256-aligned) ----------------
constexpr size_t OFF_AL    = 256;
constexpr size_t OFF_UPDF  = OFF_AL    + (size_t)M*3*4;
constexpr size_t OFF_GTC   = OFF_UPDF  + (size_t)M*4;
constexpr size_t OFF_SMI   = OFF_GTC   + (size_t)M*4;
constexpr size_t OFF_PERM  = OFF_SMI   + (size_t)M*4;
constexpr size_t OFF_AP    = OFF_PERM  + (size_t)M*4;            // M x 192 fp16 (tsm24)
constexpr size_t OFF_BQ    = OFF_AP    + (size_t)M*KP2*2;        // N x 192 fp16
constexpr size_t OFF_MFP   = OFF_BQ    + (size_t)N*KP2*2;        // N x 192 fp16
constexpr size_t OFF_MIDH  = OFF_MFP   + (size_t)N*KP2*2;        // (M+256) x 12 hi slots
constexpr size_t OFF_PAV   = OFF_MIDH  + (size_t)(M+256)*192;    // NSPA x M
constexpr size_t OFF_PAI   = OFF_PAV   + (size_t)NSPA*M*4;
constexpr size_t OFF_PB    = OFF_PAI   + (size_t)NSPA*M*4;       // NSPB x N x 20
constexpr size_t OFF_POS   = OFF_PB    + (size_t)NSPB*N*OUT*4;
constexpr size_t OFF_MAXV  = OFF_POS   + (size_t)N*4;
constexpr size_t OFF_AMAX  = OFF_MAXV  + (size_t)N*4;
constexpr size_t OFF_FLAGS = OFF_AMAX  + (size_t)N*4;            // 256 B
constexpr size_t OFF_CNT   = OFF_FLAGS + 256;                    // 256 B (zeroed w/ flags)
constexpr size_t OFF_CUR   = OFF_CNT   + 256;                    // 256 B (zeroed w/ flags)
constexpr size_t OFF_NQ4   = OFF_CUR   + 256;                    // N x float4 {ox,oy,oz,nmf2}
constexpr size_t OFF_SIDEQ = OFF_NQ4   + (size_t)N*16;           // (M+256) x float4 {m2,mx,my,mz}
constexpr size_t OFF_SIDEC = OFF_SIDEQ + (size_t)(M+256)*16;     // (M+256) int cls

// ---------------------------------------------------------------- fused prep
// 512 blocks x 64 threads: blocks [0,256) m-side (inline 4x4 inverse + class
// hist), blocks [256,512) n-side (+ pos=-1 init, replacing a 32 KB memset).
__global__ void k_prep(const float* __restrict__ ssf, const float* __restrict__ scoords,
                       const float* __restrict__ gt, const int* __restrict__ ran_mask,
                       const float* __restrict__ posses,
                       const float* __restrict__ mf, const float* __restrict__ ori,
                       float* __restrict__ al, _Float16* __restrict__ aP,
                       float* __restrict__ updf, int* __restrict__ gtcls,
                       int* __restrict__ cnt,
                       _Float16* __restrict__ bQ, _Float16* __restrict__ mfP,
                       float4* __restrict__ nq4, int* __restrict__ pos) {
    const int tt = threadIdx.x;          // 0..63
    if (blockIdx.x < 256) {
        // ---------------- m-side ----------------
        __shared__ int hcnt[OUT];
        __shared__ float sdiff[12];
        if (tt == 0) {   // inline inv(posses[1]) @ posses[0], rows 0..2
            float a[4][8];
            for (int i = 0; i < 4; i++)
                for (int j = 0; j < 4; j++) {
                    a[i][j]     = posses[16 + i*4 + j];
                    a[i][4 + j] = (i == j) ? 1.f : 0.f;
                }
            for (int col = 0; col < 4; col++) {
                int piv = col; float mx = fabsf(a[col][col]);
                for (int r = col + 1; r < 4; r++) {
                    float v = fabsf(a[r][col]);
                    if (v > mx) { mx = v; piv = r; }
                }
                if (piv != col)
                    for (int j = 0; j < 8; j++) { float t2 = a[col][j]; a[col][j] = a[piv][j]; a[piv][j] = t2; }
                float inv = 1.0f / a[col][col];
                for (int j = 0; j < 8; j++) a[col][j] *= inv;
                for (int r = 0; r < 4; r++) {
                    if (r == col) continue;
                    float f = a[r][col];
                    for (int j = 0; j < 8; j++) a[r][j] -= f * a[col][j];
                }
            }
            for (int i = 0; i < 3; i++)
                for (int j = 0; j < 4; j++) {
                    float s2 = 0.f;
                    for (int k = 0; k < 4; k++) s2 += a[i][4 + k] * posses[k*4 + j];
                    sdiff[i*4 + j] = s2;
                }
        }
        if (tt < OUT) hcnt[tt] = 0;
        __syncthreads();
        const int m = blockIdx.x * 32 + (tt >> 1);
        const int h = tt & 1;
        const float4* r4 = (const float4*)(ssf + (size_t)m * C);
        float4 row[12]; float s = 0.f;
        #pragma unroll
        for (int c = 0; c < 12; c++) {
            float4 v = r4[h*12 + c];
            row[c] = v;
            s += v.x*v.x + v.y*v.y + v.z*v.z + v.w*v.w;
        }
        s += __shfl_xor(s, 1, 64);
        float scale = 256.0f / sqrtf(s);
        h8* dst = (h8*)aP;
        #pragma unroll
        for (int qq = 0; qq < 6; qq++) {
            int q = h*6 + qq;
            float4 u = row[2*qq], v = row[2*qq+1];
            float xs[8] = {u.x,u.y,u.z,u.w,v.x,v.y,v.z,v.w};
            h8 hi, lo;
            #pragma unroll
            for (int e = 0; e < 8; e++) {
                float xv = xs[e] * scale;
                _Float16 hh = (_Float16)xv;
                hi[e] = hh;
                lo[e] = (_Float16)(xv - (float)hh);
            }
            dst[tsm24(m, q)]      = hi;
            dst[tsm24(m, 12 + q)] = lo;
        }
        if (h == 0) {
            float x = scoords[m*3], y = scoords[m*3+1], z = scoords[m*3+2];
            #pragma unroll
            for (int j = 0; j < 3; j++)
                al[m*3 + j] = sdiff[j*4+0]*x + sdiff[j*4+1]*y + sdiff[j*4+2]*z + sdiff[j*4+3];
            int best = 0; float bv = gt[(size_t)m*OUT];
            #pragma unroll
            for (int k = 1; k < OUT; k++) {
                float v = gt[(size_t)m*OUT + k];
                if (v > bv) { bv = v; best = k; }
            }
            gtcls[m] = best;
            bool upd = (best < 9 || m < LG || ran_mask[m] == 1);
            updf[m] = upd ? 1.f : 0.f;
            if (upd) atomicAdd(&hcnt[best], 1);
        }
        __syncthreads();
        if (tt < OUT) atomicAdd(&cnt[tt], hcnt[tt]);
    } else {
        // ---------------- n-side ----------------
        const int bb = blockIdx.x - 256;
        if (tt < 32) pos[bb*32 + tt] = -1;        // replaces pos memset
        const int n = bb * 32 + (tt >> 1);
        const int h = tt & 1;
        const float4* r4 = (const float4*)(mf + (size_t)n * C);
        float4 row[12]; float s = 0.f;
        #pragma unroll
        for (int c = 0; c < 12; c++) {
            float4 v = r4[h*12 + c];
            row[c] = v;
            s += v.x*v.x + v.y*v.y + v.z*v.z + v.w*v.w;
        }
        s += __shfl_xor(s, 1, 64);
        if (h == 0) {
            float4 o;
            o.x = ori[n*3]; o.y = ori[n*3+1]; o.z = ori[n*3+2]; o.w = s;
            nq4[n] = o;
        }
        float scn = 256.0f / sqrtf(s);
        h8* dB = (h8*)bQ;
        h8* dF = (h8*)mfP;
        #pragma unroll
        for (int qq = 0; qq < 6; qq++) {
            int q = h*6 + qq;
            float4 u = row[2*qq], v = row[2*qq+1];
            float xs[8] = {u.x,u.y,u.z,u.w,v.x,v.y,v.z,v.w};
            h8 hiN, loN, hiF, loF;
            #pragma unroll
            for (int e = 0; e < 8; e++) {
                float xn = xs[e] * scn;
                _Float16 hn = (_Float16)xn;
                hiN[e] = hn; loN[e] = (_Float16)(xn - (float)hn);
                float xf = xs[e] * 256.0f;
                _Float16 hf = (_Float16)xf;
                hiF[e] = hf; loF[e] = (_Float16)(xf - (float)hf);
            }
            dB[tsm24(n, q)]    = hiN;
            dB[tsm24(n, 12+q)] = loN;
            dF[tsm24(n, q)]    = hiF;
            dF[tsm24(n, 12+q)] = loF;
        }
    }
}

// ---------------------------------------------------------------- pass A: MFMA argmin
// EXACT round-9 structure (best measured: 54.8 us).
__global__ __launch_bounds__(1024, 1) void k_argmin(
        const _Float16* __restrict__ aP, const _Float16* __restrict__ bQ,
        const float* __restrict__ al, const float4* __restrict__ nq4,
        float* __restrict__ pav, int* __restrict__ pai) {
    __shared__ h8 sA[24*128];          // 48 KB resident full-K
    __shared__ h8 sB[2][24*128];       // 2 x 48 KB streamed (128 n-cols/tile)
    __shared__ float xv[4*128];
    __shared__ int   xi[4*128];
    __shared__ float4 sMs[128];        // {4axL,4ayL,4azL,-2|a|^2 L} per m-row
    const int t = threadIdx.x;
    const int wave = t >> 6, lane = t & 63;
    const int col = lane & 15, quad = lane >> 4;
    const int wm = wave >> 2, wn = wave & 3;     // 4m x 4n
    const int m0 = blockIdx.x * 128;
    const int sp = blockIdx.y;

    {   // stage resident A + first streamed tile async
        const h8* gA = (const h8*)aP + (size_t)blockIdx.x * 3072;
        #pragma unroll
        for (int q = 0; q < 3; q++) gl_lds16(gA + q*1024 + t, sA + q*1024 + t);
        const h8* g = (const h8*)bQ + (size_t)sp * 3072;
        #pragma unroll
        for (int q = 0; q < 3; q++) gl_lds16(g + q*1024 + t, sB[0] + q*1024 + t);
    }
    if (t < 128) {   // per-m expanded terms into LDS (log2e pre-folded)
        float ax = al[(m0+t)*3+0], ay = al[(m0+t)*3+1], az = al[(m0+t)*3+2];
        sMs[t] = (float4){4.0f*LOG2E*ax, 4.0f*LOG2E*ay, 4.0f*LOG2E*az,
                          -2.0f*LOG2E*(ax*ax+ay*ay+az*az)};
    }
    float best[8]; int bidx[8];
    #pragma unroll
    for (int e = 0; e < 8; e++) { best[e] = 3.4e38f; bidx[e] = 0; }

    __syncthreads();                       // sA + sB[0] + sMs visible

    // hoist resident-A fragments to registers (loop-invariant): 48 VGPR
    h8 ahR[3][2], aloR[3][2];
    #pragma unroll
    for (int ks = 0; ks < 3; ks++) {
        const int hs = ks*4 + quad;
        #pragma unroll
        for (int i = 0; i < 2; i++) {
            int ml = wm*32 + i*16 + col;
            ahR[ks][i]  = sA[hs*128 + ml];
            aloR[ks][i] = sA[(12+hs)*128 + ml];
        }
    }

    const int NT = (N/128) / NSPA;         // 16 tiles per slice
    int cur = 0;
    f4 acc[2][2];
    for (int u = 0; u < NT; u++) {
        const int tile = sp + u*NSPA;
        if (u + 1 < NT) {                  // prefetch next tile into other buffer
            const h8* g = (const h8*)bQ + (size_t)(sp + (u+1)*NSPA) * 3072;
            #pragma unroll
            for (int q = 0; q < 3; q++) gl_lds16(g + q*1024 + t, sB[cur^1] + q*1024 + t);
        }
        #pragma unroll
        for (int i = 0; i < 2; i++)
            #pragma unroll
            for (int j = 0; j < 2; j++) acc[i][j] = (f4){0.f,0.f,0.f,0.f};

        const h8* sBc = sB[cur];
        #pragma unroll
        for (int ks = 0; ks < 3; ks++) {
            const int hs = ks*4 + quad;        // hi slot; lo slot = 12+hs
            h8 bh[2], blo[2];
            #pragma unroll
            for (int j = 0; j < 2; j++) {
                int r = wn*32 + j*16 + col;
                bh[j]  = sBc[hs*128 + r];
                blo[j] = sBc[(12+hs)*128 + r];
            }
            #pragma unroll
            for (int i = 0; i < 2; i++)
                #pragma unroll
                for (int j = 0; j < 2; j++) {
                    acc[i][j] = __builtin_amdgcn_mfma_f32_16x16x32_f16(ahR[ks][i],  bh[j],  acc[i][j], 0, 0, 0);
                    acc[i][j] = __builtin_amdgcn_mfma_f32_16x16x32_f16(ahR[ks][i],  blo[j], acc[i][j], 0, 0, 0);
                    acc[i][j] = __builtin_amdgcn_mfma_f32_16x16x32_f16(aloR[ks][i], bh[j],  acc[i][j], 0, 0, 0);
                }
        }
        // epilogue: running per-lane argmin (e-outer, native exp2)
        const int n0t = tile * 128;
        float4 o4[2]; float bn[2]; int nidx[2];
        #pragma unroll
        for (int j = 0; j < 2; j++) {
            nidx[j] = n0t + wn*32 + j*16 + col;
            o4[j] = nq4[nidx[j]];
            bn[j] = -2.0f*LOG2E*(o4[j].x*o4[j].x + o4[j].y*o4[j].y + o4[j].z*o4[j].z);
        }
        #pragma unroll
        for (int e = 0; e < 8; e++) {
            int ml = wm*32 + (e>>2)*16 + quad*4 + (e&3);
            float4 sm = sMs[ml];
            #pragma unroll
            for (int j = 0; j < 2; j++) {
                float dot = acc[e>>2][j][e&3];
                float c = sm.w + bn[j];
                c = fmaf(sm.z, o4[j].z, c);
                c = fmaf(sm.y, o4[j].y, c);
                c = fmaf(sm.x, o4[j].x, c);
                float sim = fmaf(dot, -(1.0f/65536.0f), 2.0f) - fexp2(c);
                if (sim < best[e]) { best[e] = sim; bidx[e] = nidx[j]; }
            }
        }
        __syncthreads();      // prefetch landed + all waves done reading sB[cur]
        cur ^= 1;
    }
    // butterfly over 16 col-lanes, once per block
    #pragma unroll
    for (int e = 0; e < 8; e++) {
        float bv = best[e]; int bi = bidx[e];
        #pragma unroll
        for (int d = 1; d < 16; d <<= 1) {
            float ov = __shfl_xor(bv, d, 64);
            int   oi = __shfl_xor(bi, d, 64);
            if (ov < bv || (ov == bv && oi < bi)) { bv = ov; bi = oi; }
        }
        best[e] = bv; bidx[e] = bi;
    }
    if (col == 0) {
        #pragma unroll
        for (int e = 0; e < 8; e++) {
            int ml = wm*32 + (e>>2)*16 + quad*4 + (e&3);
            xv[wn*128 + ml] = best[e];
            xi[wn*128 + ml] = bidx[e];
        }
    }
    __syncthreads();
    if (t < 128) {   // single writer per (sp, m)
        float bv = xv[t]; int bi = xi[t];
        #pragma unroll
        for (int w = 1; w < 4; w++) {
            float v = xv[w*128 + t]; int i2 = xi[w*128 + t];
            if (v < bv || (v == bv && i2 < bi)) { bv = v; bi = i2; }
        }
        pav[(size_t)sp * M + m0 + t] = bv;
        pai[(size_t)sp * M + m0 + t] = bi;
    }
}

// ---------------------------------------------------------------- permute
// Counting-sort placement with per-thread redundant prefix from cnt; cursor[]
// zeroed by the single memset. Also folds the 4-way argmin reduce.
__global__ void k_permute(const float* __restrict__ pav, const int* __restrict__ pai,
                          const int* __restrict__ gtcls, const float* __restrict__ updf,
                          const int* __restrict__ cnt, int* __restrict__ cursor,
                          int* __restrict__ perm,
                          int* __restrict__ smi, float* __restrict__ out_smi) {
    int m = blockIdx.x * 256 + threadIdx.x;
    if (m >= M) return;
    float best = 3.4e38f; int bidx = 0;
    for (int sp = 0; sp < NSPA; sp++) {
        float v = pav[(size_t)sp * M + m];
        int   i = pai[(size_t)sp * M + m];
        if (v < best || (v == best && i < bidx)) { best = v; bidx = i; }
    }
    smi[m] = bidx;
    out_smi[m] = (float)bidx;
    if (updf[m] == 0.f) return;
    int cls = gtcls[m];
    int base = 0;
    #pragma unroll
    for (int k = 0; k < OUT; k++) base += (k < cls) ? cnt[k] : 0;
    int p = base + atomicAdd(&cursor[cls], 1);
    perm[p] = m;
}

// gather sorted+compacted mid rows, HI SLOTS ONLY (12/row) into compact midH;
// packs per-row side data {m2,mx,my,mz} + cls for k_uw. mact derived from cnt.
__global__ void k_gather_sorted(const int* __restrict__ cnt, const int* __restrict__ perm,
                                const int* __restrict__ smi, const int* __restrict__ gtcls,
                                const _Float16* __restrict__ mfP, const float4* __restrict__ nq4,
                                _Float16* __restrict__ midH,
                                float4* __restrict__ sideQ, int* __restrict__ sideC) {
    __shared__ int smact;
    if (threadIdx.x == 0) {
        int s = 0;
        #pragma unroll
        for (int k = 0; k < OUT; k++) s += cnt[k];
        smact = s;
    }
    __syncthreads();
    int mact = smact;
    int mpad = ((mact + 255) >> 8) << 8;
    int tid = blockIdx.x * 256 + threadIdx.x;
    int rr = tid / 12;
    int q  = tid - rr * 12;          // hi slot 0..11
    if (rr >= mpad) return;
    h8* dst = (h8*)midH;
    size_t didx = ((size_t)(rr >> 7) * 12 + q) * 128 + (rr & 127);
    if (rr < mact) {
        int m = perm[rr];
        int s = smi[m];
        dst[didx] = ((const h8*)mfP)[tsm24(s, q)];
        if (q == 0) {
            float4 o = nq4[s];
            float4 sq;
            sq.x = o.w;                       // |feat|^2
            sq.y = o.x; sq.z = o.y; sq.w = o.z;
            sideQ[rr] = sq;
            sideC[rr] = gtcls[m];
        }
    } else {
        dst[didx] = (h8)(_Float16)0.f;
        if (q == 0) {
            sideQ[rr] = (float4){1e9f, 0.f, 0.f, 0.f};   // fd=1e9 -> w = 0 exactly
            sideC[rr] = 0;
        }
    }
}

// ---------------------------------------------------------------- pass B: MFMA class-binned sums
// EXACT round-12 version (hi-only B, 256-col dbuf tiles, hoisted resident
// fragments, boundary masked class-range reduce, native exp2).
__global__ __launch_bounds__(1024, 1) void k_uw(
        const _Float16* __restrict__ mfP, const _Float16* __restrict__ midH,
        const float4* __restrict__ nq4,
        const float4* __restrict__ sideQ, const int* __restrict__ sideC,
        const int* __restrict__ cnt, float* __restrict__ pb) {
    __shared__ h8 sN[24*128];          // 48 KB resident n-rows (hi+lo)
    __shared__ h8 sB[2][2*12*128];     // 2 x 48 KB streamed mid tiles (hi only, 256 cols)
    __shared__ float bins[128*21];
    __shared__ float4 sSa[128];        // {ox,oy,oz,-8L|o|^2} per n-row
    __shared__ float  sSb[128];        // nmf2 per n-row
    __shared__ int    snmac;
    const int t = threadIdx.x;
    const int wave = t >> 6, lane = t & 63;
    const int col = lane & 15, quad = lane >> 4;
    const int wm = wave >> 2, wn = wave & 3;     // 4m x 4n
    const int n0 = blockIdx.x * 128;
    const int sp = blockIdx.y;

    if (t == 0) {
        int s = 0;
        #pragma unroll
        for (int k = 0; k < OUT; k++) s += cnt[k];
        snmac = (s + 255) >> 8;
    }
    __syncthreads();
    const int nmac = snmac;

    {   // stage resident n-rows + first streamed tile async
        const h8* gN = (const h8*)mfP + (size_t)blockIdx.x * 3072;
        #pragma unroll
        for (int q = 0; q < 3; q++) gl_lds16(gN + q*1024 + t, sN + q*1024 + t);
        if (sp < nmac) {
            const h8* g = (const h8*)midH + (size_t)(2*sp) * 1536;
            #pragma unroll
            for (int q = 0; q < 3; q++) gl_lds16(g + q*1024 + t, sB[0] + q*1024 + t);
        }
    }
    if (t < 128) {   // per-n expanded terms into LDS (log2e pre-folded)
        float4 q = nq4[n0 + t];
        sSa[t] = (float4){q.x, q.y, q.z, -8.0f*LOG2E*(q.x*q.x + q.y*q.y + q.z*q.z)};
        sSb[t] = q.w;
    }
    for (int i = t; i < 128*21; i += 1024) bins[i] = 0.f;

    __syncthreads();                   // sN + sB[0] + side + bins visible

    // hoist resident-N fragments to registers (loop-invariant): 48 VGPR
    h8 ahR[3][2], aloR[3][2];
    #pragma unroll
    for (int ks = 0; ks < 3; ks++) {
        const int hs = ks*4 + quad;
        #pragma unroll
        for (int i = 0; i < 2; i++) {
            int ml = wm*32 + i*16 + col;
            ahR[ks][i]  = sN[hs*128 + ml];
            aloR[ks][i] = sN[(12+hs)*128 + ml];
        }
    }

    int cur = 0;
    f4 acc[2][4];
    for (int mt = sp; mt < nmac; mt += NSPB) {
        const int mb = mt * 256;
        if (mt + NSPB < nmac) {        // prefetch next tile into other buffer
            const h8* g = (const h8*)midH + (size_t)(2*(mt + NSPB)) * 1536;
            #pragma unroll
            for (int q = 0; q < 3; q++) gl_lds16(g + q*1024 + t, sB[cur^1] + q*1024 + t);
        }
        #pragma unroll
        for (int i = 0; i < 2; i++)
            #pragma unroll
            for (int j = 0; j < 4; j++) acc[i][j] = (f4){0.f,0.f,0.f,0.f};

        const h8* sBc = sB[cur];
        #pragma unroll
        for (int ks = 0; ks < 3; ks++) {
            const int hs = ks*4 + quad;        // hi slot 0..11
            h8 bh[4];
            #pragma unroll
            for (int j = 0; j < 4; j++) {
                int r = wn*64 + j*16 + col;
                int tb = (r >> 7) * 1536, rl = r & 127;
                bh[j]  = sBc[tb + hs*128 + rl];
            }
            #pragma unroll
            for (int i = 0; i < 2; i++)
                #pragma unroll
                for (int j = 0; j < 4; j++) {
                    acc[i][j] = __builtin_amdgcn_mfma_f32_16x16x32_f16(ahR[ks][i],  bh[j], acc[i][j], 0, 0, 0);
                    acc[i][j] = __builtin_amdgcn_mfma_f32_16x16x32_f16(aloR[ks][i], bh[j], acc[i][j], 0, 0, 0);
                }
        }
        // epilogue: fold into class bins
        {
            float m2[4], mx16[4], my16[4], mz16[4], bm[4]; int pc[4];
            #pragma unroll
            for (int j = 0; j < 4; j++) {
                int mm = mb + wn*64 + j*16 + col;
                float4 sq = sideQ[mm];
                m2[j] = sq.x;
                mx16[j] = 16.0f*LOG2E*sq.y; my16[j] = 16.0f*LOG2E*sq.z; mz16[j] = 16.0f*LOG2E*sq.w;
                bm[j] = -8.0f*LOG2E*(sq.y*sq.y + sq.z*sq.z + sq.w*sq.w);
                pc[j] = sideC[mm];
            }
            int seg0 = sideC[mb + wn*64];
            int seg1 = sideC[mb + wn*64 + 63];
            if (seg0 == seg1) {   // wave's 64 cols uniform class
                #pragma unroll
                for (int e = 0; e < 8; e++) {
                    int nl = wm*32 + (e>>2)*16 + quad*4 + (e&3);
                    float4 sa = sSa[nl];
                    float nn = sSb[nl];
                    float rs = 0.f;
                    #pragma unroll
                    for (int j = 0; j < 4; j++) {
                        float dot = acc[e>>2][j][e&3];
                        float tt = fmaf(dot, -2.0f*(1.0f/65536.0f), nn + m2[j]);
                        float fd = fmaxf(tt, 0.0f);
                        float c = sa.w + bm[j];
                        c = fmaf(sa.z, mz16[j], c);
                        c = fmaf(sa.y, my16[j], c);
                        c = fmaf(sa.x, mx16[j], c);
                        rs += fexp2(fmaf(fd, -(0.5f/0.09f)*LOG2E, c));
                    }
                    rs += __shfl_xor(rs, 1, 64);
                    rs += __shfl_xor(rs, 2, 64);
                    rs += __shfl_xor(rs, 4, 64);
                    rs += __shfl_xor(rs, 8, 64);
                    if (col == 0) atomicAdd(&bins[nl*21 + seg0], rs);
                }
            } else {
                // boundary: classes form contiguous [seg0,seg1] (counting sort)
                // -> masked shfl-reduce per class, ONE atomic per (quad,class).
                #pragma unroll
                for (int e = 0; e < 8; e++) {
                    int nl = wm*32 + (e>>2)*16 + quad*4 + (e&3);
                    float4 sa = sSa[nl];
                    float nn = sSb[nl];
                    float w[4];
                    #pragma unroll
                    for (int j = 0; j < 4; j++) {
                        float dot = acc[e>>2][j][e&3];
                        float tt = fmaf(dot, -2.0f*(1.0f/65536.0f), nn + m2[j]);
                        float fd = fmaxf(tt, 0.0f);
                        float c = sa.w + bm[j];
                        c = fmaf(sa.z, mz16[j], c);
                        c = fmaf(sa.y, my16[j], c);
                        c = fmaf(sa.x, mx16[j], c);
                        w[j] = fexp2(fmaf(fd, -(0.5f/0.09f)*LOG2E, c));
                    }
                    for (int cc = seg0; cc <= seg1; cc++) {
                        float rs = 0.f;
                        #pragma unroll
                        for (int j = 0; j < 4; j++) rs += (pc[j] == cc) ? w[j] : 0.f;
                        rs += __shfl_xor(rs, 1, 64);
                        rs += __shfl_xor(rs, 2, 64);
                        rs += __shfl_xor(rs, 4, 64);
                        rs += __shfl_xor(rs, 8, 64);
                        if (col == 0) atomicAdd(&bins[nl*21 + cc], rs);
                    }
                }
            }
        }
        __syncthreads();   // prefetch landed + all waves done reading sB[cur]
        cur ^= 1;
    }
    __syncthreads();
    for (int i = t; i < 128*OUT; i += 1024) {
        int loc = i / OUT, k = i - loc*OUT;
        pb[((size_t)sp*N + n0 + loc)*OUT + k] = bins[loc*21 + k];
    }
}

// ---------------------------------------------------------------- uw final
// Also computes maxv/amax/flags (k_trust_pre folded in; the spu row is
// already in registers here). k_scatter patches rewritten rows afterwards.
__global__ void k_uw_final(const float* __restrict__ pb, const float* __restrict__ svp,
                           float* __restrict__ out_uw, float* __restrict__ out_spu,
                           float* __restrict__ maxv, int* __restrict__ amax,
                           int* __restrict__ flags) {
    int n = blockIdx.x * 256 + threadIdx.x;
    if (n >= N) return;
    float s[OUT];
    #pragma unroll
    for (int k = 0; k < OUT; k++) s[k] = 0.f;
    for (int sp = 0; sp < NSPB; sp++) {
        size_t base = ((size_t)sp * N + n) * OUT;
        #pragma unroll
        for (int k = 0; k < OUT; k++) s[k] += pb[base + k];
    }
    float tot = 0.f;
    #pragma unroll
    for (int k = 0; k < OUT; k++) tot += s[k];
    float rden = 1.0f / (tot + 1e-16f);
    float p[OUT]; float mx = -3.4e38f;
    #pragma unroll
    for (int k = 0; k < OUT; k++) { p[k] = svp[(size_t)n*OUT + k]; mx = fmaxf(mx, p[k]); }
    float es = 0.f;
    #pragma unroll
    for (int k = 0; k < OUT; k++) { p[k] = __expf(p[k] - mx); es += p[k]; }
    float res = 1.0f / es;
    float bestv = -3.4e38f; int bi = 0;
    #pragma unroll
    for (int k = 0; k < OUT; k++) {
        float uw = s[k] * rden;
        float sv = 0.5f * (p[k] * res) + 0.5f * uw;
        out_uw[(size_t)n*OUT + k] = uw;
        out_spu[(size_t)n*OUT + k] = sv;
        if (sv > bestv) { bestv = sv; bi = k; }
    }
    maxv[n] = bestv; amax[n] = bi;
    if (bestv >= 0.9f) atomicOr(&flags[1], 1);
}

// ---------------------------------------------------------------- scatter (fused, 1 block)
// Rewritten rows become one-hot -> patch maxv/amax/flags for them too.
__global__ void k_scatter(const int* __restrict__ smi, const int* __restrict__ gtcls,
                          float* __restrict__ spu, int* __restrict__ pos,
                          float* __restrict__ maxv, int* __restrict__ amax,
                          int* __restrict__ flags) {
    __shared__ int sflag;
    const int t = threadIdx.x;
    if (t == 0) sflag = 0;
    __syncthreads();
    float v[2]; int idx[2];
    #pragma unroll
    for (int k = 0; k < 2; k++) {
        int i = t + k*1024;
        idx[k] = smi[i];
        v[k] = spu[(size_t)idx[k]*OUT + gtcls[i]];
        if (v[k] > 0.1f) atomicOr(&sflag, 1);
        atomicMax(&pos[idx[k]], i);
    }
    __syncthreads();
    const bool any = (sflag != 0);
    bool wrote = false;
    #pragma unroll
    for (int k = 0; k < 2; k++) {
        int i = t + k*1024;
        if (atomicMax(&pos[idx[k]], -1) != i) continue;   // not last writer
        bool tmp = any ? (v[k] > 0.1f) : (v[k] > 0.0f);
        if (!tmp) continue;
        int cls = gtcls[i];
        #pragma unroll
        for (int kk = 0; kk < OUT; kk++)
            spu[(size_t)idx[k]*OUT + kk] = (kk == cls) ? 1.0f : 0.0f;
        maxv[idx[k]] = 1.0f;
        amax[idx[k]] = cls;
        wrote = true;
    }
    if (wrote) atomicOr(&flags[1], 1);    // 1.0 >= 0.9
}

// ---------------------------------------------------------------- finalize
__global__ void k_finalize(const float* __restrict__ mf, const float* __restrict__ ori,
                           const float* __restrict__ maxv, const int* __restrict__ amax,
                           const int* __restrict__ flags,
                           float* __restrict__ out_trust, float* __restrict__ out_mf,
                           float* __restrict__ out_ori, float* __restrict__ out_pre) {
    int n = blockIdx.x * 256 + threadIdx.x;
    if (n >= N) return;
    float mv = maxv[n];
    bool tr = flags[1] ? (mv >= 0.9f) : (mv >= 0.85f);
    float m = tr ? 1.f : 0.f;
    out_trust[n] = m;
    const float4* src = (const float4*)(mf + (size_t)n * C);
    float4* dst = (float4*)(out_mf + (size_t)n * C);
    #pragma unroll
    for (int c = 0; c < 24; c++) {
        float4 v = src[c];
        v.x *= m; v.y *= m; v.z *= m; v.w *= m;
        dst[c] = v;
    }
    out_ori[n*3]   = ori[n*3]   * m;
    out_ori[n*3+1] = ori[n*3+1] * m;
    out_ori[n*3+2] = ori[n*3+2] * m;
    int bi = amax[n];
    #pragma unroll
    for (int k = 0; k < OUT; k++) out_pre[(size_t)n*OUT + k] = (k == bi) ? m : 0.f;
}

// ---------------------------------------------------------------- launch
extern "C" void kernel_launch(void* const* d_in, const int* in_sizes, int n_in,
                              void* d_out, int out_size, void* d_ws, size_t ws_size,
                              hipStream_t stream) {
    (void)in_sizes; (void)n_in; (void)out_size; (void)ws_size;
    const float* ssf     = (const float*)d_in[0];
    const float* scoords = (const float*)d_in[1];
    const float* gt      = (const float*)d_in[2];
    const float* svp     = (const float*)d_in[3];
    const float* mf      = (const float*)d_in[4];
    const float* ori     = (const float*)d_in[5];
    const float* posses  = (const float*)d_in[6];
    const int*   ran     = (const int*)d_in[7];

    float* out = (float*)d_out;
    float* out_trust = out;
    float* out_mf    = out_trust + N;
    float* out_ori   = out_mf + (size_t)N*C;
    float* out_pre   = out_ori + (size_t)N*3;
    float* out_uw    = out_pre + (size_t)N*OUT;
    float* out_spu   = out_uw  + (size_t)N*OUT;
    float* out_smi   = out_spu + (size_t)N*OUT;

    char* ws = (char*)d_ws;
    float*     w_al    = (float*)(ws + OFF_AL);
    float*     w_updf  = (float*)(ws + OFF_UPDF);
    int*       w_gtc   = (int*)(ws + OFF_GTC);
    int*       w_smi   = (int*)(ws + OFF_SMI);
    int*       w_perm  = (int*)(ws + OFF_PERM);
    _Float16*  w_aP    = (_Float16*)(ws + OFF_AP);
    _Float16*  w_bQ    = (_Float16*)(ws + OFF_BQ);
    _Float16*  w_mfP   = (_Float16*)(ws + OFF_MFP);
    _Float16*  w_midH  = (_Float16*)(ws + OFF_MIDH);
    float*     w_pav   = (float*)(ws + OFF_PAV);
    int*       w_pai   = (int*)(ws + OFF_PAI);
    float*     w_pb    = (float*)(ws + OFF_PB);
    int*       w_pos   = (int*)(ws + OFF_POS);
    float*     w_maxv  = (float*)(ws + OFF_MAXV);
    int*       w_amax  = (int*)(ws + OFF_AMAX);
    int*       w_flags = (int*)(ws + OFF_FLAGS);
    int*       w_cnt   = (int*)(ws + OFF_CNT);
    int*       w_cur   = (int*)(ws + OFF_CUR);
    float4*    w_nq4   = (float4*)(ws + OFF_NQ4);
    float4*    w_sideQ = (float4*)(ws + OFF_SIDEQ);
    int*       w_sideC = (int*)(ws + OFF_SIDEC);

    // single memset: flags (256) + cnt (256) + cursor (256), contiguous
    hipMemsetAsync(w_flags, 0, 768, stream);

    k_prep<<<512, 64, 0, stream>>>(ssf, scoords, gt, ran, posses, mf, ori,
                                   w_al, w_aP, w_updf, w_gtc, w_cnt,
                                   w_bQ, w_mfP, w_nq4, w_pos);
    k_argmin<<<dim3(M/128, NSPA), 1024, 0, stream>>>(w_aP, w_bQ, w_al, w_nq4, w_pav, w_pai);
    k_permute<<<M/256, 256, 0, stream>>>(w_pav, w_pai, w_gtc, w_updf, w_cnt, w_cur,
                                         w_perm, w_smi, out_smi);
    k_gather_sorted<<<((M+256)*12)/256, 256, 0, stream>>>(w_cnt, w_perm, w_smi, w_gtc,
                                                          w_mfP, w_nq4,
                                                          w_midH, w_sideQ, w_sideC);
    k_uw<<<dim3(N/128, NSPB), 1024, 0, stream>>>(w_mfP, w_midH, w_nq4,
                                                 w_sideQ, w_sideC, w_cnt, w_pb);
    k_uw_final<<<N/256, 256, 0, stream>>>(w_pb, svp, out_uw, out_spu,
                                          w_maxv, w_amax, w_flags);
    k_scatter<<<1, 1024, 0, stream>>>(w_smi, w_gtc, out_spu, w_pos,
                                      w_maxv, w_amax, w_flags);
    k_finalize<<<N/256, 256, 0, stream>>>(mf, ori, w_maxv, w_amax, w_flags,
                                          out_trust, out_mf, out_ori, out_pre);
}

// Round 14
// 218.296 us; speedup vs baseline: 1.1182x; 1.0221x over previous
//
#include <hip/hip_runtime.h>
#include <math.h>

#define N 8192
#define M 8192
#define C 96
#define OUT 20
#define LG 2048

#define KP2 192     // stored K per row: [hi(96)|lo(96)] fp16, 24 h8 slots
#define NSPA 4      // y-slices pass A
#define NSPB 4      // y-slices pass B
#define LOG2E 1.4426950408889634f

typedef _Float16 h8 __attribute__((ext_vector_type(8)));
typedef float    f4 __attribute__((ext_vector_type(4)));

// native v_exp_f32 (exp2f = libm-precise __ocml call, ~10 instrs; this is 1)
__device__ __forceinline__ float fexp2(float x) { return __builtin_amdgcn_exp2f(x); }

// async global->LDS, 16B per lane, no VGPR round-trip (m97 path)
__device__ __forceinline__ void gl_lds16(const h8* g, h8* l) {
    __builtin_amdgcn_global_load_lds(
        (const __attribute__((address_space(1))) unsigned int*)g,
        (__attribute__((address_space(3))) unsigned int*)l,
        16, 0, 0);
}

// tile-slot-major h8 index: rows grouped in 128-row tiles, slot-major inside
__device__ __forceinline__ size_t tsm24(int row, int slot) {
    return ((size_t)(row >> 7) * 24 + slot) * 128 + (row & 127);
}

// ---------------- workspace layout (bytes, all 256-aligned) ----------------
constexpr size_t OFF_AL    = 256;
constexpr size_t OFF_UPDF  = OFF_AL    + (size_t)M*3*4;
constexpr size_t OFF_GTC   = OFF_UPDF  + (size_t)M*4;
constexpr size_t OFF_SMI   = OFF_GTC   + (size_t)M*4;
constexpr size_t OFF_PERM  = OFF_SMI   + (size_t)M*4;
constexpr size_t OFF_AP    = OFF_PERM  + (size_t)M*4;            // M x 192 fp16 (tsm24)
constexpr size_t OFF_BQ    = OFF_AP    + (size_t)M*KP2*2;        // N x 192 fp16
constexpr size_t OFF_MFP   = OFF_BQ    + (size_t)N*KP2*2;        // N x 192 fp16
constexpr size_t OFF_MIDH  = OFF_MFP   + (size_t)N*KP2*2;        // (M+256) x 12 hi slots
constexpr size_t OFF_PAV   = OFF_MIDH  + (size_t)(M+256)*192;    // NSPA x M
constexpr size_t OFF_PAI   = OFF_PAV   + (size_t)NSPA*M*4;
constexpr size_t OFF_PB    = OFF_PAI   + (size_t)NSPA*M*4;       // NSPB x N x 20
constexpr size_t OFF_POS   = OFF_PB    + (size_t)NSPB*N*OUT*4;
constexpr size_t OFF_MAXV  = OFF_POS   + (size_t)N*4;
constexpr size_t OFF_AMAX  = OFF_MAXV  + (size_t)N*4;
constexpr size_t OFF_FLAGS = OFF_AMAX  + (size_t)N*4;            // 256 B
constexpr size_t OFF_CNT   = OFF_FLAGS + 256;                    // 256 B (zeroed w/ flags)
constexpr size_t OFF_CUR   = OFF_CNT   + 256;                    // 256 B (zeroed w/ flags)
constexpr size_t OFF_NQ4   = OFF_CUR   + 256;                    // N x float4 {ox,oy,oz,nmf2}
constexpr size_t OFF_SIDEQ = OFF_NQ4   + (size_t)N*16;           // (M+256) x float4 {m2,mx,my,mz}
constexpr size_t OFF_SIDEC = OFF_SIDEQ + (size_t)(M+256)*16;     // (M+256) int cls

// ---------------------------------------------------------------- fused prep
// 1024 blocks x 64 threads, 4 threads/row (16 rows/block): blocks [0,512) do
// the m-side (inline 4x4 inverse + class hist), [512,1024) the n-side
// (+ pos=-1 init). 4 waves/CU (2x the TLP of the 512-block version).
__global__ void k_prep(const float* __restrict__ ssf, const float* __restrict__ scoords,
                       const float* __restrict__ gt, const int* __restrict__ ran_mask,
                       const float* __restrict__ posses,
                       const float* __restrict__ mf, const float* __restrict__ ori,
                       float* __restrict__ al, _Float16* __restrict__ aP,
                       float* __restrict__ updf, int* __restrict__ gtcls,
                       int* __restrict__ cnt,
                       _Float16* __restrict__ bQ, _Float16* __restrict__ mfP,
                       float4* __restrict__ nq4, int* __restrict__ pos) {
    const int tt = threadIdx.x;          // 0..63
    if (blockIdx.x < 512) {
        // ---------------- m-side ----------------
        __shared__ int hcnt[OUT];
        __shared__ float sdiff[12];
        if (tt == 0) {   // inline inv(posses[1]) @ posses[0], rows 0..2
            float a[4][8];
            for (int i = 0; i < 4; i++)
                for (int j = 0; j < 4; j++) {
                    a[i][j]     = posses[16 + i*4 + j];
                    a[i][4 + j] = (i == j) ? 1.f : 0.f;
                }
            for (int col = 0; col < 4; col++) {
                int piv = col; float mx = fabsf(a[col][col]);
                for (int r = col + 1; r < 4; r++) {
                    float v = fabsf(a[r][col]);
                    if (v > mx) { mx = v; piv = r; }
                }
                if (piv != col)
                    for (int j = 0; j < 8; j++) { float t2 = a[col][j]; a[col][j] = a[piv][j]; a[piv][j] = t2; }
                float inv = 1.0f / a[col][col];
                for (int j = 0; j < 8; j++) a[col][j] *= inv;
                for (int r = 0; r < 4; r++) {
                    if (r == col) continue;
                    float f = a[r][col];
                    for (int j = 0; j < 8; j++) a[r][j] -= f * a[col][j];
                }
            }
            for (int i = 0; i < 3; i++)
                for (int j = 0; j < 4; j++) {
                    float s2 = 0.f;
                    for (int k = 0; k < 4; k++) s2 += a[i][4 + k] * posses[k*4 + j];
                    sdiff[i*4 + j] = s2;
                }
        }
        if (tt < OUT) hcnt[tt] = 0;
        __syncthreads();
        const int m = blockIdx.x * 16 + (tt >> 2);
        const int h = tt & 3;
        const float4* r4 = (const float4*)(ssf + (size_t)m * C);
        float4 row[6]; float s = 0.f;
        #pragma unroll
        for (int c = 0; c < 6; c++) {
            float4 v = r4[h*6 + c];
            row[c] = v;
            s += v.x*v.x + v.y*v.y + v.z*v.z + v.w*v.w;
        }
        s += __shfl_xor(s, 1, 64);
        s += __shfl_xor(s, 2, 64);
        float scale = 256.0f / sqrtf(s);
        h8* dst = (h8*)aP;
        #pragma unroll
        for (int qq = 0; qq < 3; qq++) {
            int q = h*3 + qq;
            float4 u = row[2*qq], v = row[2*qq+1];
            float xs[8] = {u.x,u.y,u.z,u.w,v.x,v.y,v.z,v.w};
            h8 hi, lo;
            #pragma unroll
            for (int e = 0; e < 8; e++) {
                float xv = xs[e] * scale;
                _Float16 hh = (_Float16)xv;
                hi[e] = hh;
                lo[e] = (_Float16)(xv - (float)hh);
            }
            dst[tsm24(m, q)]      = hi;
            dst[tsm24(m, 12 + q)] = lo;
        }
        if (h == 0) {
            float x = scoords[m*3], y = scoords[m*3+1], z = scoords[m*3+2];
            #pragma unroll
            for (int j = 0; j < 3; j++)
                al[m*3 + j] = sdiff[j*4+0]*x + sdiff[j*4+1]*y + sdiff[j*4+2]*z + sdiff[j*4+3];
            int best = 0; float bv = gt[(size_t)m*OUT];
            #pragma unroll
            for (int k = 1; k < OUT; k++) {
                float v = gt[(size_t)m*OUT + k];
                if (v > bv) { bv = v; best = k; }
            }
            gtcls[m] = best;
            bool upd = (best < 9 || m < LG || ran_mask[m] == 1);
            updf[m] = upd ? 1.f : 0.f;
            if (upd) atomicAdd(&hcnt[best], 1);
        }
        __syncthreads();
        if (tt < OUT) atomicAdd(&cnt[tt], hcnt[tt]);
    } else {
        // ---------------- n-side ----------------
        const int bb = blockIdx.x - 512;
        if (tt < 16) pos[bb*16 + tt] = -1;        // replaces pos memset
        const int n = bb * 16 + (tt >> 2);
        const int h = tt & 3;
        const float4* r4 = (const float4*)(mf + (size_t)n * C);
        float4 row[6]; float s = 0.f;
        #pragma unroll
        for (int c = 0; c < 6; c++) {
            float4 v = r4[h*6 + c];
            row[c] = v;
            s += v.x*v.x + v.y*v.y + v.z*v.z + v.w*v.w;
        }
        s += __shfl_xor(s, 1, 64);
        s += __shfl_xor(s, 2, 64);
        if (h == 0) {
            float4 o;
            o.x = ori[n*3]; o.y = ori[n*3+1]; o.z = ori[n*3+2]; o.w = s;
            nq4[n] = o;
        }
        float scn = 256.0f / sqrtf(s);
        h8* dB = (h8*)bQ;
        h8* dF = (h8*)mfP;
        #pragma unroll
        for (int qq = 0; qq < 3; qq++) {
            int q = h*3 + qq;
            float4 u = row[2*qq], v = row[2*qq+1];
            float xs[8] = {u.x,u.y,u.z,u.w,v.x,v.y,v.z,v.w};
            h8 hiN, loN, hiF, loF;
            #pragma unroll
            for (int e = 0; e < 8; e++) {
                float xn = xs[e] * scn;
                _Float16 hn = (_Float16)xn;
                hiN[e] = hn; loN[e] = (_Float16)(xn - (float)hn);
                float xf = xs[e] * 256.0f;
                _Float16 hf = (_Float16)xf;
                hiF[e] = hf; loF[e] = (_Float16)(xf - (float)hf);
            }
            dB[tsm24(n, q)]    = hiN;
            dB[tsm24(n, 12+q)] = loN;
            dF[tsm24(n, q)]    = hiF;
            dF[tsm24(n, 12+q)] = loF;
        }
    }
}

// ---------------------------------------------------------------- pass A: MFMA argmin
// EXACT round-13 version (best measured: 54.8 us). Frozen.
__global__ __launch_bounds__(1024, 1) void k_argmin(
        const _Float16* __restrict__ aP, const _Float16* __restrict__ bQ,
        const float* __restrict__ al, const float4* __restrict__ nq4,
        float* __restrict__ pav, int* __restrict__ pai) {
    __shared__ h8 sA[24*128];          // 48 KB resident full-K
    __shared__ h8 sB[2][24*128];       // 2 x 48 KB streamed (128 n-cols/tile)
    __shared__ float xv[4*128];
    __shared__ int   xi[4*128];
    __shared__ float4 sMs[128];        // {4axL,4ayL,4azL,-2|a|^2 L} per m-row
    const int t = threadIdx.x;
    const int wave = t >> 6, lane = t & 63;
    const int col = lane & 15, quad = lane >> 4;
    const int wm = wave >> 2, wn = wave & 3;     // 4m x 4n
    const int m0 = blockIdx.x * 128;
    const int sp = blockIdx.y;

    {   // stage resident A + first streamed tile async
        const h8* gA = (const h8*)aP + (size_t)blockIdx.x * 3072;
        #pragma unroll
        for (int q = 0; q < 3; q++) gl_lds16(gA + q*1024 + t, sA + q*1024 + t);
        const h8* g = (const h8*)bQ + (size_t)sp * 3072;
        #pragma unroll
        for (int q = 0; q < 3; q++) gl_lds16(g + q*1024 + t, sB[0] + q*1024 + t);
    }
    if (t < 128) {   // per-m expanded terms into LDS (log2e pre-folded)
        float ax = al[(m0+t)*3+0], ay = al[(m0+t)*3+1], az = al[(m0+t)*3+2];
        sMs[t] = (float4){4.0f*LOG2E*ax, 4.0f*LOG2E*ay, 4.0f*LOG2E*az,
                          -2.0f*LOG2E*(ax*ax+ay*ay+az*az)};
    }
    float best[8]; int bidx[8];
    #pragma unroll
    for (int e = 0; e < 8; e++) { best[e] = 3.4e38f; bidx[e] = 0; }

    __syncthreads();                       // sA + sB[0] + sMs visible

    // hoist resident-A fragments to registers (loop-invariant): 48 VGPR
    h8 ahR[3][2], aloR[3][2];
    #pragma unroll
    for (int ks = 0; ks < 3; ks++) {
        const int hs = ks*4 + quad;
        #pragma unroll
        for (int i = 0; i < 2; i++) {
            int ml = wm*32 + i*16 + col;
            ahR[ks][i]  = sA[hs*128 + ml];
            aloR[ks][i] = sA[(12+hs)*128 + ml];
        }
    }

    const int NT = (N/128) / NSPA;         // 16 tiles per slice
    int cur = 0;
    f4 acc[2][2];
    for (int u = 0; u < NT; u++) {
        const int tile = sp + u*NSPA;
        if (u + 1 < NT) {                  // prefetch next tile into other buffer
            const h8* g = (const h8*)bQ + (size_t)(sp + (u+1)*NSPA) * 3072;
            #pragma unroll
            for (int q = 0; q < 3; q++) gl_lds16(g + q*1024 + t, sB[cur^1] + q*1024 + t);
        }
        #pragma unroll
        for (int i = 0; i < 2; i++)
            #pragma unroll
            for (int j = 0; j < 2; j++) acc[i][j] = (f4){0.f,0.f,0.f,0.f};

        const h8* sBc = sB[cur];
        #pragma unroll
        for (int ks = 0; ks < 3; ks++) {
            const int hs = ks*4 + quad;        // hi slot; lo slot = 12+hs
            h8 bh[2], blo[2];
            #pragma unroll
            for (int j = 0; j < 2; j++) {
                int r = wn*32 + j*16 + col;
                bh[j]  = sBc[hs*128 + r];
                blo[j] = sBc[(12+hs)*128 + r];
            }
            #pragma unroll
            for (int i = 0; i < 2; i++)
                #pragma unroll
                for (int j = 0; j < 2; j++) {
                    acc[i][j] = __builtin_amdgcn_mfma_f32_16x16x32_f16(ahR[ks][i],  bh[j],  acc[i][j], 0, 0, 0);
                    acc[i][j] = __builtin_amdgcn_mfma_f32_16x16x32_f16(ahR[ks][i],  blo[j], acc[i][j], 0, 0, 0);
                    acc[i][j] = __builtin_amdgcn_mfma_f32_16x16x32_f16(aloR[ks][i], bh[j],  acc[i][j], 0, 0, 0);
                }
        }
        // epilogue: running per-lane argmin (e-outer, native exp2)
        const int n0t = tile * 128;
        float4 o4[2]; float bn[2]; int nidx[2];
        #pragma unroll
        for (int j = 0; j < 2; j++) {
            nidx[j] = n0t + wn*32 + j*16 + col;
            o4[j] = nq4[nidx[j]];
            bn[j] = -2.0f*LOG2E*(o4[j].x*o4[j].x + o4[j].y*o4[j].y + o4[j].z*o4[j].z);
        }
        #pragma unroll
        for (int e = 0; e < 8; e++) {
            int ml = wm*32 + (e>>2)*16 + quad*4 + (e&3);
            float4 sm = sMs[ml];
            #pragma unroll
            for (int j = 0; j < 2; j++) {
                float dot = acc[e>>2][j][e&3];
                float c = sm.w + bn[j];
                c = fmaf(sm.z, o4[j].z, c);
                c = fmaf(sm.y, o4[j].y, c);
                c = fmaf(sm.x, o4[j].x, c);
                float sim = fmaf(dot, -(1.0f/65536.0f), 2.0f) - fexp2(c);
                if (sim < best[e]) { best[e] = sim; bidx[e] = nidx[j]; }
            }
        }
        __syncthreads();      // prefetch landed + all waves done reading sB[cur]
        cur ^= 1;
    }
    // butterfly over 16 col-lanes, once per block
    #pragma unroll
    for (int e = 0; e < 8; e++) {
        float bv = best[e]; int bi = bidx[e];
        #pragma unroll
        for (int d = 1; d < 16; d <<= 1) {
            float ov = __shfl_xor(bv, d, 64);
            int   oi = __shfl_xor(bi, d, 64);
            if (ov < bv || (ov == bv && oi < bi)) { bv = ov; bi = oi; }
        }
        best[e] = bv; bidx[e] = bi;
    }
    if (col == 0) {
        #pragma unroll
        for (int e = 0; e < 8; e++) {
            int ml = wm*32 + (e>>2)*16 + quad*4 + (e&3);
            xv[wn*128 + ml] = best[e];
            xi[wn*128 + ml] = bidx[e];
        }
    }
    __syncthreads();
    if (t < 128) {   // single writer per (sp, m)
        float bv = xv[t]; int bi = xi[t];
        #pragma unroll
        for (int w = 1; w < 4; w++) {
            float v = xv[w*128 + t]; int i2 = xi[w*128 + t];
            if (v < bv || (v == bv && i2 < bi)) { bv = v; bi = i2; }
        }
        pav[(size_t)sp * M + m0 + t] = bv;
        pai[(size_t)sp * M + m0 + t] = bi;
    }
}

// ---------------------------------------------------------------- permute
// Re-gridded to 128 blocks x 64 threads (was 32x256 = only 32 CUs busy).
__global__ void k_permute(const float* __restrict__ pav, const int* __restrict__ pai,
                          const int* __restrict__ gtcls, const float* __restrict__ updf,
                          const int* __restrict__ cnt, int* __restrict__ cursor,
                          int* __restrict__ perm,
                          int* __restrict__ smi, float* __restrict__ out_smi) {
    int m = blockIdx.x * 64 + threadIdx.x;
    if (m >= M) return;
    float best = 3.4e38f; int bidx = 0;
    for (int sp = 0; sp < NSPA; sp++) {
        float v = pav[(size_t)sp * M + m];
        int   i = pai[(size_t)sp * M + m];
        if (v < best || (v == best && i < bidx)) { best = v; bidx = i; }
    }
    smi[m] = bidx;
    out_smi[m] = (float)bidx;
    if (updf[m] == 0.f) return;
    int cls = gtcls[m];
    int base = 0;
    #pragma unroll
    for (int k = 0; k < OUT; k++) base += (k < cls) ? cnt[k] : 0;
    int p = base + atomicAdd(&cursor[cls], 1);
    perm[p] = m;
}

// gather sorted+compacted mid rows, HI SLOTS ONLY (12/row) into compact midH;
// packs per-row side data {m2,mx,my,mz} + cls for k_uw. mact derived from cnt.
__global__ void k_gather_sorted(const int* __restrict__ cnt, const int* __restrict__ perm,
                                const int* __restrict__ smi, const int* __restrict__ gtcls,
                                const _Float16* __restrict__ mfP, const float4* __restrict__ nq4,
                                _Float16* __restrict__ midH,
                                float4* __restrict__ sideQ, int* __restrict__ sideC) {
    __shared__ int smact;
    if (threadIdx.x == 0) {
        int s = 0;
        #pragma unroll
        for (int k = 0; k < OUT; k++) s += cnt[k];
        smact = s;
    }
    __syncthreads();
    int mact = smact;
    int mpad = ((mact + 255) >> 8) << 8;
    int tid = blockIdx.x * 256 + threadIdx.x;
    int rr = tid / 12;
    int q  = tid - rr * 12;          // hi slot 0..11
    if (rr >= mpad) return;
    h8* dst = (h8*)midH;
    size_t didx = ((size_t)(rr >> 7) * 12 + q) * 128 + (rr & 127);
    if (rr < mact) {
        int m = perm[rr];
        int s = smi[m];
        dst[didx] = ((const h8*)mfP)[tsm24(s, q)];
        if (q == 0) {
            float4 o = nq4[s];
            float4 sq;
            sq.x = o.w;                       // |feat|^2
            sq.y = o.x; sq.z = o.y; sq.w = o.z;
            sideQ[rr] = sq;
            sideC[rr] = gtcls[m];
        }
    } else {
        dst[didx] = (h8)(_Float16)0.f;
        if (q == 0) {
            sideQ[rr] = (float4){1e9f, 0.f, 0.f, 0.f};   // fd=1e9 -> w = 0 exactly
            sideC[rr] = 0;
        }
    }
}

// ---------------------------------------------------------------- pass B: MFMA class-binned sums
// EXACT round-13 version. Frozen.
__global__ __launch_bounds__(1024, 1) void k_uw(
        const _Float16* __restrict__ mfP, const _Float16* __restrict__ midH,
        const float4* __restrict__ nq4,
        const float4* __restrict__ sideQ, const int* __restrict__ sideC,
        const int* __restrict__ cnt, float* __restrict__ pb) {
    __shared__ h8 sN[24*128];          // 48 KB resident n-rows (hi+lo)
    __shared__ h8 sB[2][2*12*128];     // 2 x 48 KB streamed mid tiles (hi only, 256 cols)
    __shared__ float bins[128*21];
    __shared__ float4 sSa[128];        // {ox,oy,oz,-8L|o|^2} per n-row
    __shared__ float  sSb[128];        // nmf2 per n-row
    __shared__ int    snmac;
    const int t = threadIdx.x;
    const int wave = t >> 6, lane = t & 63;
    const int col = lane & 15, quad = lane >> 4;
    const int wm = wave >> 2, wn = wave & 3;     // 4m x 4n
    const int n0 = blockIdx.x * 128;
    const int sp = blockIdx.y;

    if (t == 0) {
        int s = 0;
        #pragma unroll
        for (int k = 0; k < OUT; k++) s += cnt[k];
        snmac = (s + 255) >> 8;
    }
    __syncthreads();
    const int nmac = snmac;

    {   // stage resident n-rows + first streamed tile async
        const h8* gN = (const h8*)mfP + (size_t)blockIdx.x * 3072;
        #pragma unroll
        for (int q = 0; q < 3; q++) gl_lds16(gN + q*1024 + t, sN + q*1024 + t);
        if (sp < nmac) {
            const h8* g = (const h8*)midH + (size_t)(2*sp) * 1536;
            #pragma unroll
            for (int q = 0; q < 3; q++) gl_lds16(g + q*1024 + t, sB[0] + q*1024 + t);
        }
    }
    if (t < 128) {   // per-n expanded terms into LDS (log2e pre-folded)
        float4 q = nq4[n0 + t];
        sSa[t] = (float4){q.x, q.y, q.z, -8.0f*LOG2E*(q.x*q.x + q.y*q.y + q.z*q.z)};
        sSb[t] = q.w;
    }
    for (int i = t; i < 128*21; i += 1024) bins[i] = 0.f;

    __syncthreads();                   // sN + sB[0] + side + bins visible

    // hoist resident-N fragments to registers (loop-invariant): 48 VGPR
    h8 ahR[3][2], aloR[3][2];
    #pragma unroll
    for (int ks = 0; ks < 3; ks++) {
        const int hs = ks*4 + quad;
        #pragma unroll
        for (int i = 0; i < 2; i++) {
            int ml = wm*32 + i*16 + col;
            ahR[ks][i]  = sN[hs*128 + ml];
            aloR[ks][i] = sN[(12+hs)*128 + ml];
        }
    }

    int cur = 0;
    f4 acc[2][4];
    for (int mt = sp; mt < nmac; mt += NSPB) {
        const int mb = mt * 256;
        if (mt + NSPB < nmac) {        // prefetch next tile into other buffer
            const h8* g = (const h8*)midH + (size_t)(2*(mt + NSPB)) * 1536;
            #pragma unroll
            for (int q = 0; q < 3; q++) gl_lds16(g + q*1024 + t, sB[cur^1] + q*1024 + t);
        }
        #pragma unroll
        for (int i = 0; i < 2; i++)
            #pragma unroll
            for (int j = 0; j < 4; j++) acc[i][j] = (f4){0.f,0.f,0.f,0.f};

        const h8* sBc = sB[cur];
        #pragma unroll
        for (int ks = 0; ks < 3; ks++) {
            const int hs = ks*4 + quad;        // hi slot 0..11
            h8 bh[4];
            #pragma unroll
            for (int j = 0; j < 4; j++) {
                int r = wn*64 + j*16 + col;
                int tb = (r >> 7) * 1536, rl = r & 127;
                bh[j]  = sBc[tb + hs*128 + rl];
            }
            #pragma unroll
            for (int i = 0; i < 2; i++)
                #pragma unroll
                for (int j = 0; j < 4; j++) {
                    acc[i][j] = __builtin_amdgcn_mfma_f32_16x16x32_f16(ahR[ks][i],  bh[j], acc[i][j], 0, 0, 0);
                    acc[i][j] = __builtin_amdgcn_mfma_f32_16x16x32_f16(aloR[ks][i], bh[j], acc[i][j], 0, 0, 0);
                }
        }
        // epilogue: fold into class bins
        {
            float m2[4], mx16[4], my16[4], mz16[4], bm[4]; int pc[4];
            #pragma unroll
            for (int j = 0; j < 4; j++) {
                int mm = mb + wn*64 + j*16 + col;
                float4 sq = sideQ[mm];
                m2[j] = sq.x;
                mx16[j] = 16.0f*LOG2E*sq.y; my16[j] = 16.0f*LOG2E*sq.z; mz16[j] = 16.0f*LOG2E*sq.w;
                bm[j] = -8.0f*LOG2E*(sq.y*sq.y + sq.z*sq.z + sq.w*sq.w);
                pc[j] = sideC[mm];
            }
            int seg0 = sideC[mb + wn*64];
            int seg1 = sideC[mb + wn*64 + 63];
            if (seg0 == seg1) {   // wave's 64 cols uniform class
                #pragma unroll
                for (int e = 0; e < 8; e++) {
                    int nl = wm*32 + (e>>2)*16 + quad*4 + (e&3);
                    float4 sa = sSa[nl];
                    float nn = sSb[nl];
                    float rs = 0.f;
                    #pragma unroll
                    for (int j = 0; j < 4; j++) {
                        float dot = acc[e>>2][j][e&3];
                        float tt = fmaf(dot, -2.0f*(1.0f/65536.0f), nn + m2[j]);
                        float fd = fmaxf(tt, 0.0f);
                        float c = sa.w + bm[j];
                        c = fmaf(sa.z, mz16[j], c);
                        c = fmaf(sa.y, my16[j], c);
                        c = fmaf(sa.x, mx16[j], c);
                        rs += fexp2(fmaf(fd, -(0.5f/0.09f)*LOG2E, c));
                    }
                    rs += __shfl_xor(rs, 1, 64);
                    rs += __shfl_xor(rs, 2, 64);
                    rs += __shfl_xor(rs, 4, 64);
                    rs += __shfl_xor(rs, 8, 64);
                    if (col == 0) atomicAdd(&bins[nl*21 + seg0], rs);
                }
            } else {
                // boundary: classes form contiguous [seg0,seg1] (counting sort)
                // -> masked shfl-reduce per class, ONE atomic per (quad,class).
                #pragma unroll
                for (int e = 0; e < 8; e++) {
                    int nl = wm*32 + (e>>2)*16 + quad*4 + (e&3);
                    float4 sa = sSa[nl];
                    float nn = sSb[nl];
                    float w[4];
                    #pragma unroll
                    for (int j = 0; j < 4; j++) {
                        float dot = acc[e>>2][j][e&3];
                        float tt = fmaf(dot, -2.0f*(1.0f/65536.0f), nn + m2[j]);
                        float fd = fmaxf(tt, 0.0f);
                        float c = sa.w + bm[j];
                        c = fmaf(sa.z, mz16[j], c);
                        c = fmaf(sa.y, my16[j], c);
                        c = fmaf(sa.x, mx16[j], c);
                        w[j] = fexp2(fmaf(fd, -(0.5f/0.09f)*LOG2E, c));
                    }
                    for (int cc = seg0; cc <= seg1; cc++) {
                        float rs = 0.f;
                        #pragma unroll
                        for (int j = 0; j < 4; j++) rs += (pc[j] == cc) ? w[j] : 0.f;
                        rs += __shfl_xor(rs, 1, 64);
                        rs += __shfl_xor(rs, 2, 64);
                        rs += __shfl_xor(rs, 4, 64);
                        rs += __shfl_xor(rs, 8, 64);
                        if (col == 0) atomicAdd(&bins[nl*21 + cc], rs);
                    }
                }
            }
        }
        __syncthreads();   // prefetch landed + all waves done reading sB[cur]
        cur ^= 1;
    }
    __syncthreads();
    for (int i = t; i < 128*OUT; i += 1024) {
        int loc = i / OUT, k = i - loc*OUT;
        pb[((size_t)sp*N + n0 + loc)*OUT + k] = bins[loc*21 + k];
    }
}

// ---------------------------------------------------------------- uw final
// Re-gridded to 128 blocks x 64 threads (was 32x256). Also computes
// maxv/amax/flags (trust_pre folded); k_scatter patches rewritten rows.
__global__ void k_uw_final(const float* __restrict__ pb, const float* __restrict__ svp,
                           float* __restrict__ out_uw, float* __restrict__ out_spu,
                           float* __restrict__ maxv, int* __restrict__ amax,
                           int* __restrict__ flags) {
    int n = blockIdx.x * 64 + threadIdx.x;
    if (n >= N) return;
    float s[OUT];
    #pragma unroll
    for (int k = 0; k < OUT; k++) s[k] = 0.f;
    for (int sp = 0; sp < NSPB; sp++) {
        size_t base = ((size_t)sp * N + n) * OUT;
        #pragma unroll
        for (int k = 0; k < OUT; k++) s[k] += pb[base + k];
    }
    float tot = 0.f;
    #pragma unroll
    for (int k = 0; k < OUT; k++) tot += s[k];
    float rden = 1.0f / (tot + 1e-16f);
    float p[OUT]; float mx = -3.4e38f;
    #pragma unroll
    for (int k = 0; k < OUT; k++) { p[k] = svp[(size_t)n*OUT + k]; mx = fmaxf(mx, p[k]); }
    float es = 0.f;
    #pragma unroll
    for (int k = 0; k < OUT; k++) { p[k] = __expf(p[k] - mx); es += p[k]; }
    float res = 1.0f / es;
    float bestv = -3.4e38f; int bi = 0;
    #pragma unroll
    for (int k = 0; k < OUT; k++) {
        float uw = s[k] * rden;
        float sv = 0.5f * (p[k] * res) + 0.5f * uw;
        out_uw[(size_t)n*OUT + k] = uw;
        out_spu[(size_t)n*OUT + k] = sv;
        if (sv > bestv) { bestv = sv; bi = k; }
    }
    maxv[n] = bestv; amax[n] = bi;
    if (bestv >= 0.9f) atomicOr(&flags[1], 1);
}

// ---------------------------------------------------------------- scatter (fused, 1 block)
// Rewritten rows become one-hot -> patch maxv/amax/flags for them too.
__global__ void k_scatter(const int* __restrict__ smi, const int* __restrict__ gtcls,
                          float* __restrict__ spu, int* __restrict__ pos,
                          float* __restrict__ maxv, int* __restrict__ amax,
                          int* __restrict__ flags) {
    __shared__ int sflag;
    const int t = threadIdx.x;
    if (t == 0) sflag = 0;
    __syncthreads();
    float v[2]; int idx[2];
    #pragma unroll
    for (int k = 0; k < 2; k++) {
        int i = t + k*1024;
        idx[k] = smi[i];
        v[k] = spu[(size_t)idx[k]*OUT + gtcls[i]];
        if (v[k] > 0.1f) atomicOr(&sflag, 1);
        atomicMax(&pos[idx[k]], i);
    }
    __syncthreads();
    const bool any = (sflag != 0);
    bool wrote = false;
    #pragma unroll
    for (int k = 0; k < 2; k++) {
        int i = t + k*1024;
        if (atomicMax(&pos[idx[k]], -1) != i) continue;   // not last writer
        bool tmp = any ? (v[k] > 0.1f) : (v[k] > 0.0f);
        if (!tmp) continue;
        int cls = gtcls[i];
        #pragma unroll
        for (int kk = 0; kk < OUT; kk++)
            spu[(size_t)idx[k]*OUT + kk] = (kk == cls) ? 1.0f : 0.0f;
        maxv[idx[k]] = 1.0f;
        amax[idx[k]] = cls;
        wrote = true;
    }
    if (wrote) atomicOr(&flags[1], 1);    // 1.0 >= 0.9
}

// ---------------------------------------------------------------- finalize
// Re-gridded to 128 blocks x 64 threads (was 32x256).
__global__ void k_finalize(const float* __restrict__ mf, const float* __restrict__ ori,
                           const float* __restrict__ maxv, const int* __restrict__ amax,
                           const int* __restrict__ flags,
                           float* __restrict__ out_trust, float* __restrict__ out_mf,
                           float* __restrict__ out_ori, float* __restrict__ out_pre) {
    int n = blockIdx.x * 64 + threadIdx.x;
    if (n >= N) return;
    float mv = maxv[n];
    bool tr = flags[1] ? (mv >= 0.9f) : (mv >= 0.85f);
    float m = tr ? 1.f : 0.f;
    out_trust[n] = m;
    const float4* src = (const float4*)(mf + (size_t)n * C);
    float4* dst = (float4*)(out_mf + (size_t)n * C);
    #pragma unroll
    for (int c = 0; c < 24; c++) {
        float4 v = src[c];
        v.x *= m; v.y *= m; v.z *= m; v.w *= m;
        dst[c] = v;
    }
    out_ori[n*3]   = ori[n*3]   * m;
    out_ori[n*3+1] = ori[n*3+1] * m;
    out_ori[n*3+2] = ori[n*3+2] * m;
    int bi = amax[n];
    #pragma unroll
    for (int k = 0; k < OUT; k++) out_pre[(size_t)n*OUT + k] = (k == bi) ? m : 0.f;
}

// ---------------------------------------------------------------- launch
extern "C" void kernel_launch(void* const* d_in, const int* in_sizes, int n_in,
                              void* d_out, int out_size, void* d_ws, size_t ws_size,
                              hipStream_t stream) {
    (void)in_sizes; (void)n_in; (void)out_size; (void)ws_size;
    const float* ssf     = (const float*)d_in[0];
    const float* scoords = (const float*)d_in[1];
    const float* gt      = (const float*)d_in[2];
    const float* svp     = (const float*)d_in[3];
    const float* mf      = (const float*)d_in[4];
    const float* ori     = (const float*)d_in[5];
    const float* posses  = (const float*)d_in[6];
    const int*   ran     = (const int*)d_in[7];

    float* out = (float*)d_out;
    float* out_trust = out;
    float* out_mf    = out_trust + N;
    float* out_ori   = out_mf + (size_t)N*C;
    float* out_pre   = out_ori + (size_t)N*3;
    float* out_uw    = out_pre + (size_t)N*OUT;
    float* out_spu   = out_uw  + (size_t)N*OUT;
    float* out_smi   = out_spu + (size_t)N*OUT;

    char* ws = (char*)d_ws;
    float*     w_al    = (float*)(ws + OFF_AL);
    float*     w_updf  = (float*)(ws + OFF_UPDF);
    int*       w_gtc   = (int*)(ws + OFF_GTC);
    int*       w_smi   = (int*)(ws + OFF_SMI);
    int*       w_perm  = (int*)(ws + OFF_PERM);
    _Float16*  w_aP    = (_Float16*)(ws + OFF_AP);
    _Float16*  w_bQ    = (_Float16*)(ws + OFF_BQ);
    _Float16*  w_mfP   = (_Float16*)(ws + OFF_MFP);
    _Float16*  w_midH  = (_Float16*)(ws + OFF_MIDH);
    float*     w_pav   = (float*)(ws + OFF_PAV);
    int*       w_pai   = (int*)(ws + OFF_PAI);
    float*     w_pb    = (float*)(ws + OFF_PB);
    int*       w_pos   = (int*)(ws + OFF_POS);
    float*     w_maxv  = (float*)(ws + OFF_MAXV);
    int*       w_amax  = (int*)(ws + OFF_AMAX);
    int*       w_flags = (int*)(ws + OFF_FLAGS);
    int*       w_cnt   = (int*)(ws + OFF_CNT);
    int*       w_cur   = (int*)(ws + OFF_CUR);
    float4*    w_nq4   = (float4*)(ws + OFF_NQ4);
    float4*    w_sideQ = (float4*)(ws + OFF_SIDEQ);
    int*       w_sideC = (int*)(ws + OFF_SIDEC);

    // single memset: flags (256) + cnt (256) + cursor (256), contiguous
    hipMemsetAsync(w_flags, 0, 768, stream);

    k_prep<<<1024, 64, 0, stream>>>(ssf, scoords, gt, ran, posses, mf, ori,
                                    w_al, w_aP, w_updf, w_gtc, w_cnt,
                                    w_bQ, w_mfP, w_nq4, w_pos);
    k_argmin<<<dim3(M/128, NSPA), 1024, 0, stream>>>(w_aP, w_bQ, w_al, w_nq4, w_pav, w_pai);
    k_permute<<<M/64, 64, 0, stream>>>(w_pav, w_pai, w_gtc, w_updf, w_cnt, w_cur,
                                       w_perm, w_smi, out_smi);
    k_gather_sorted<<<((M+256)*12)/256, 256, 0, stream>>>(w_cnt, w_perm, w_smi, w_gtc,
                                                          w_mfP, w_nq4,
                                                          w_midH, w_sideQ, w_sideC);
    k_uw<<<dim3(N/128, NSPB), 1024, 0, stream>>>(w_mfP, w_midH, w_nq4,
                                                 w_sideQ, w_sideC, w_cnt, w_pb);
    k_uw_final<<<N/64, 64, 0, stream>>>(w_pb, svp, out_uw, out_spu,
                                        w_maxv, w_amax, w_flags);
    k_scatter<<<1, 1024, 0, stream>>>(w_smi, w_gtc, out_spu, w_pos,
                                      w_maxv, w_amax, w_flags);
    k_finalize<<<N/64, 64, 0, stream>>>(mf, ori, w_maxv, w_amax, w_flags,
                                        out_trust, out_mf, out_ori, out_pre);
}